// Round 1
// baseline (347.586 us; speedup 1.0000x reference)
//
#include <hip/hip_runtime.h>

typedef unsigned short u16;
typedef unsigned char u8;
typedef __bf16 bf16x8 __attribute__((ext_vector_type(8)));
typedef float f32x4 __attribute__((ext_vector_type(4)));
typedef u16 u16x8 __attribute__((ext_vector_type(8)));

__device__ __forceinline__ float bf2f(u16 u) {
    union { unsigned i; float f; } c; c.i = ((unsigned)u) << 16; return c.f;
}
__device__ __forceinline__ u16 f2bf(float f) {
    union { float f; unsigned i; } c; c.f = f;
    unsigned r = c.i + 0x7FFFu + ((c.i >> 16) & 1u);
    return (u16)(r >> 16);
}

// async global->LDS, 16B per lane (global_load_lds_dwordx4)
__device__ __forceinline__ void gload16(const void* g, void* l) {
    __builtin_amdgcn_global_load_lds(
        (const __attribute__((address_space(1))) void*)g,
        (__attribute__((address_space(3))) void*)l, 16, 0, 0);
}

// ---------- PREP: fused [k1: shortcut LIF + transpose] + [weight levels] + [KVraw zero] ----------
// grid: 768 k1-blocks (3 c-tiles x 8 n-tiles x 32 b) + 576 weight blocks; block 256
__global__ __launch_bounds__(256) void prep(const float* __restrict__ X, u16* __restrict__ Xt,
    const float* __restrict__ qw, const float* __restrict__ kw,
    const float* __restrict__ vw, const float* __restrict__ pw,
    u16* __restrict__ W, float* __restrict__ KVraw) {
    const int bid = blockIdx.x;
    if (bid < 768) {
        __shared__ u16 s[4][128][33];
        const int c0 = (bid % 3) * 128;
        const int n0 = ((bid / 3) & 7) * 32;
        const int b = bid / 24;
        const int n_l = threadIdx.x & 31, cg = threadIdx.x >> 5;
        for (int jj = 0; jj < 16; jj++) {
            int c_l = cg + jj * 8;
            float vm = 0.f;
            #pragma unroll
            for (int t = 0; t < 4; t++) {
                float xv = X[(((long)t * 32 + b) * 384 + c0 + c_l) * 256 + n0 + n_l];
                vm += (xv - vm) * 0.5f;
                u16 sp = 0;
                if (vm >= 1.0f) { sp = 0x3F80u; vm = 0.f; }
                s[t][c_l][n_l] = sp;
            }
        }
        __syncthreads();
        const int c8 = (threadIdx.x & 15) << 3;
        const int ng = threadIdx.x >> 4;
        for (int half = 0; half < 2; half++) {
            int n = ng + half * 16;
            #pragma unroll
            for (int t = 0; t < 4; t++) {
                u16x8 v;
                #pragma unroll
                for (int j = 0; j < 8; j++) v[j] = s[t][c8 + j][n];
                *(u16x8*)&Xt[(((long)b * 256 + n0 + n) * 4 + t) * 384 + c0 + c8] = v;
            }
        }
    } else {
        const int idx = (bid - 768) * 256 + threadIdx.x;   // [0, 147456)
        const float* srcs[3] = {qw, kw, vw};
        #pragma unroll
        for (int m = 0; m < 3; m++) {
            float w = srcs[m][idx];
            u16 h0 = f2bf(w);  float r1 = w - bf2f(h0);
            u16 h1 = f2bf(r1); float r2 = r1 - bf2f(h1);
            u16 h2 = f2bf(r2);
            W[(m * 3 + 0) * 147456 + idx] = h0;
            W[(m * 3 + 1) * 147456 + idx] = h1;
            W[(m * 3 + 2) * 147456 + idx] = h2;
        }
        W[9 * 147456 + idx] = f2bf(pw[idx]);
        if (idx < 49152) KVraw[idx] = 0.f;
    }
}

// ---------- multi-level GEMM K-loop: 128x128 tile, BK=32, global_load_lds staging (m97 structure) ----------
// LDS layout: A tile [128][32] u16 at lds[0], B level p at lds[(p+1)*4096], all unpadded.
// Staging map: lane l of wave w covers row tid>>2, 16B chunk tid&3 -> LDS byte w*1024 + l*16 (linear, required).
template<int NL>
__device__ __forceinline__ void gemm_levels(const u16* __restrict__ A, const u16* __restrict__ B,
                                            long lstride, u16* lds, int m0, int n0, f32x4 (&acc)[4][4]) {
    const int tid = threadIdx.x, l = tid & 63, w = tid >> 6;
    const int wm = (w & 1) << 6, wn = (w >> 1) << 6;
    const int fr = l & 15, fq = (l >> 4) << 3;
    const int r0 = tid >> 2, c8 = (tid & 3) << 3, r1 = r0 + 64;
    const u16* Ap0 = A + (long)(m0 + r0) * 384 + c8;
    const u16* Ap1 = A + (long)(m0 + r1) * 384 + c8;
    const u16* Bp0 = B + (long)(n0 + r0) * 384 + c8;
    const u16* Bp1 = B + (long)(n0 + r1) * 384 + c8;
    u16* dA0 = &lds[r0 * 32 + c8];      // byte offset = w*1024 + l*16
    u16* dA1 = &lds[r1 * 32 + c8];
    for (int kk = 0; kk < 384; kk += 32) {
        gload16(Ap0 + kk, dA0);
        gload16(Ap1 + kk, dA1);
        #pragma unroll
        for (int p = 0; p < NL; p++) {
            gload16(Bp0 + p * lstride + kk, dA0 + (p + 1) * 4096);
            gload16(Bp1 + p * lstride + kk, dA1 + (p + 1) * 4096);
        }
        __syncthreads();   // compiler drains vmcnt(0): staged data visible
        bf16x8 af[4];
        #pragma unroll
        for (int i = 0; i < 4; i++) af[i] = *(const bf16x8*)&lds[(wm + (i << 4) + fr) * 32 + fq];
        #pragma unroll
        for (int p = 0; p < NL; p++)
            #pragma unroll
            for (int j = 0; j < 4; j++) {
                bf16x8 bfr = *(const bf16x8*)&lds[(p + 1) * 4096 + (wn + (j << 4) + fr) * 32 + fq];
                #pragma unroll
                for (int i = 0; i < 4; i++)
                    acc[i][j] = __builtin_amdgcn_mfma_f32_16x16x32_bf16(af[i], bfr, acc[i][j], 0, 0, 0);
            }
        __syncthreads();
    }
}

// ---------- K2: q/k/v conv1x1 (3-level split GEMM) + BN + LIF -> u8 spikes ----------
__global__ __launch_bounds__(256) void k2(
    const u16* __restrict__ Xt, const u16* __restrict__ Wlv,
    const float* __restrict__ g0, const float* __restrict__ b0, const float* __restrict__ m0_, const float* __restrict__ v0_,
    const float* __restrict__ g1, const float* __restrict__ b1, const float* __restrict__ m1_, const float* __restrict__ v1_,
    const float* __restrict__ g2, const float* __restrict__ b2, const float* __restrict__ m2_, const float* __restrict__ v2_,
    u8* __restrict__ oq, u8* __restrict__ ok, u8* __restrict__ ov, float* __restrict__ out1)
{
    __shared__ __attribute__((aligned(16))) u16 lds[20480];   // gemm uses 16384; tile 128x136 aliased
    const int br = blockIdx.z;
    const float* G  = br == 0 ? g0  : (br == 1 ? g1  : g2);
    const float* Be = br == 0 ? b0  : (br == 1 ? b1  : b2);
    const float* Mu = br == 0 ? m0_ : (br == 1 ? m1_ : m2_);
    const float* Va = br == 0 ? v0_ : (br == 1 ? v1_ : v2_);
    const int m0 = blockIdx.x * 128, d0 = blockIdx.y * 128;

    f32x4 acc[4][4];
    for (int i = 0; i < 4; i++) for (int j = 0; j < 4; j++)
        for (int r = 0; r < 4; r++) acc[i][j][r] = 0.f;
    gemm_levels<3>(Xt, Wlv + (long)br * 3 * 147456, 147456L, lds, m0, d0, acc);

    const int tid = threadIdx.x, l = tid & 63, w = tid >> 6;
    const int wm = (w & 1) << 6, wn = (w >> 1) << 6;
    const int fr = l & 15, fq = l >> 4;
    float sc[4], mu[4], be[4];
    #pragma unroll
    for (int j = 0; j < 4; j++) {
        int d = d0 + wn + (j << 4) + fr;
        sc[j] = G[d] / sqrtf(Va[d] + 1e-5f);
        mu[j] = Mu[d];
        be[j] = Be[d];
    }
    u16* tile = lds;
    #pragma unroll
    for (int i = 0; i < 4; i++)
        #pragma unroll
        for (int j = 0; j < 4; j++) {
            float vm = 0.f;
            #pragma unroll
            for (int r = 0; r < 4; r++) {
                float bn = (acc[i][j][r] - mu[j]) * sc[j] + be[j];
                vm += (bn - vm) * 0.5f;
                u16 s = 0;
                if (vm >= 1.0f) { s = 0x3F80u; vm = 0.f; }
                tile[(wm + (i << 4) + (fq << 2) + r) * 136 + wn + (j << 4) + fr] = s;
            }
        }
    __syncthreads();
    const int c8 = (tid & 15) << 3;
    u8* Out8 = br == 0 ? oq : (br == 1 ? ok : ov);
    #pragma unroll
    for (int p = 0; p < 8; p++) {
        int ml = (tid >> 4) + (p << 4);
        u16x8 sp = *(const u16x8*)&tile[ml * 136 + c8];
        union { u8 b[8]; uint2 u; } pk;
        #pragma unroll
        for (int r = 0; r < 8; r++) pk.b[r] = sp[r] ? 1 : 0;
        *(uint2*)&Out8[(long)(m0 + ml) * 384 + d0 + c8] = pk.u;
    }
    if (br == 2) {   // output 1: v spikes as f32 in (T,B,h,N,Ch)
        const int b = m0 >> 10, n_base = (m0 >> 2) & 255;
        const int dl = tid & 127, d = d0 + dl;
        const int h = d / 48, ch = d % 48;
        for (int q = 0; q < 64; q++) {
            int ml = (tid >> 7) + (q << 1);
            int t = ml & 3, n = n_base + (ml >> 2);
            out1[((((long)t * 32 + b) * 8 + h) * 256 + n) * 48 + ch] =
                tile[ml * 136 + dl] ? 1.0f : 0.f;
        }
    }
}

// ---------- K3a: kv partial counts (exact int), uchar4 loads ----------
// block (96,4): tidx = d-quad, tidy = t; grid (8 n-chunks, 32 b)
__global__ __launch_bounds__(384) void k3a(const u8* __restrict__ Ks, const u8* __restrict__ Vs,
                                           float* __restrict__ kv_raw) {
    const int b = blockIdx.y, nc = blockIdx.x;
    const int d4 = threadIdx.x * 4, t = threadIdx.y;
    int cnt0 = 0, cnt1 = 0, cnt2 = 0, cnt3 = 0;
    for (int nl = 0; nl < 32; nl++) {
        const long row = ((long)b * 256 + nc * 32 + nl) * 4 + t;
        uchar4 kk = *(const uchar4*)&Ks[row * 384 + d4];
        uchar4 vv = *(const uchar4*)&Vs[row * 384 + d4];
        cnt0 += (kk.x & vv.x); cnt1 += (kk.y & vv.y);
        cnt2 += (kk.z & vv.z); cnt3 += (kk.w & vv.w);
    }
    float* dst = &kv_raw[((long)t * 32 + b) * 384 + d4];
    atomicAdd(dst + 0, (float)cnt0);
    atomicAdd(dst + 1, (float)cnt1);
    atomicAdd(dst + 2, (float)cnt2);
    atomicAdd(dst + 3, (float)cnt3);
}

// ---------- K3b: LIF(kv, v_th=0.5) ----------
__global__ __launch_bounds__(384) void k3b(const float* __restrict__ kv_raw, u16* __restrict__ kvs) {
    const int b = blockIdx.x, d = threadIdx.x;
    float vm = 0.f;
    #pragma unroll
    for (int t = 0; t < 4; t++) {
        vm += (kv_raw[((long)t * 32 + b) * 384 + d] - vm) * 0.5f;
        u16 sp = 0;
        if (vm >= 0.5f) { sp = 0x3F80u; vm = 0.f; }
        kvs[((long)t * 32 + b) * 384 + d] = sp;
    }
}

// ---------- K3c: Y(bf16) = q(u8) * KV(bf16 mask) ----------
__global__ __launch_bounds__(256) void k3c(const u8* __restrict__ Qs, const u16* __restrict__ KVs,
                                           u16* __restrict__ Y) {
    const long i8 = ((long)blockIdx.x * 256 + threadIdx.x) * 8;
    const int m = (int)(i8 / 384), d8 = (int)(i8 % 384);
    const int t = m & 3, b = m >> 10;
    uint2 q8 = *(const uint2*)(Qs + i8);
    const u8* qb = (const u8*)&q8;
    u16x8 kv = *(const u16x8*)(KVs + ((long)(t * 32 + b) * 384 + d8));
    u16x8 y;
    #pragma unroll
    for (int j = 0; j < 8; j++) y[j] = qb[j] ? kv[j] : (u16)0;
    *(u16x8*)(Y + i8) = y;
}

// ---------- K4: proj GEMM + bias + BN + identity -> f32 (T,B,C,H,W) ----------
__global__ __launch_bounds__(256) void k4(
    const u16* __restrict__ Y, const u16* __restrict__ PW,
    const float* __restrict__ PB, const float* __restrict__ PG, const float* __restrict__ PBe,
    const float* __restrict__ PM, const float* __restrict__ PV,
    const float* __restrict__ X, float* __restrict__ O)
{
    __shared__ __attribute__((aligned(16))) u16 lds[20480];
    const int m0 = blockIdx.x * 128, e0 = blockIdx.y * 128;
    f32x4 acc[4][4];
    for (int i = 0; i < 4; i++) for (int j = 0; j < 4; j++)
        for (int r = 0; r < 4; r++) acc[i][j][r] = 0.f;
    gemm_levels<1>(Y, PW, 0L, lds, m0, e0, acc);

    const int tid = threadIdx.x, l = tid & 63, w = tid >> 6;
    const int wm = (w & 1) << 6, wn = (w >> 1) << 6;
    const int fr = l & 15, fq = l >> 4;
    float sc[4], mu[4], be[4], pb[4];
    #pragma unroll
    for (int j = 0; j < 4; j++) {
        int e = e0 + wn + (j << 4) + fr;
        sc[j] = PG[e] / sqrtf(PV[e] + 1e-5f);
        mu[j] = PM[e];
        be[j] = PBe[e];
        pb[j] = PB[e];
    }
    float* smemf = (float*)lds;   // 64x136 f32 tile = 34816 B <= 40960
    const int b = m0 >> 10, n_base = (m0 >> 2) & 255;
    for (int cchunk = 0; cchunk < 2; cchunk++) {
        if ((w & 1) == cchunk) {
            #pragma unroll
            for (int i = 0; i < 4; i++)
                #pragma unroll
                for (int j = 0; j < 4; j++)
                    #pragma unroll
                    for (int r = 0; r < 4; r++) {
                        float z = (acc[i][j][r] + pb[j] - mu[j]) * sc[j] + be[j];
                        smemf[((i << 4) + (fq << 2) + r) * 136 + wn + (j << 4) + fr] = z;
                    }
        }
        __syncthreads();
        const int n_l = tid & 15, eg = tid >> 4;
        #pragma unroll
        for (int ee = 0; ee < 8; ee++) {
            int e_l = eg + (ee << 4);
            #pragma unroll
            for (int t = 0; t < 4; t++) {
                float z = smemf[((n_l << 2) + t) * 136 + e_l];
                long gi = (((long)t * 32 + b) * 384 + e0 + e_l) * 256 + n_base + (cchunk << 4) + n_l;
                O[gi] = z + X[gi];
            }
        }
        __syncthreads();
    }
}

extern "C" void kernel_launch(void* const* d_in, const int* in_sizes, int n_in,
                              void* d_out, int out_size, void* d_ws, size_t ws_size,
                              hipStream_t stream) {
    (void)in_sizes; (void)n_in; (void)out_size; (void)ws_size;
    const float* x   = (const float*)d_in[0];
    const float* qw  = (const float*)d_in[1];
    const float* qg  = (const float*)d_in[2];
    const float* qb  = (const float*)d_in[3];
    const float* qm  = (const float*)d_in[4];
    const float* qv  = (const float*)d_in[5];
    const float* kw  = (const float*)d_in[6];
    const float* kg  = (const float*)d_in[7];
    const float* kb  = (const float*)d_in[8];
    const float* km  = (const float*)d_in[9];
    const float* kv  = (const float*)d_in[10];
    const float* vw  = (const float*)d_in[11];
    const float* vg  = (const float*)d_in[12];
    const float* vb  = (const float*)d_in[13];
    const float* vm  = (const float*)d_in[14];
    const float* vv  = (const float*)d_in[15];
    const float* pw  = (const float*)d_in[16];
    const float* pb  = (const float*)d_in[17];
    const float* pg  = (const float*)d_in[18];
    const float* pbe = (const float*)d_in[19];
    const float* pm  = (const float*)d_in[20];
    const float* pv  = (const float*)d_in[21];

    // out0 (50.3 MB) as scratch until k4 writes it:
    //   Qs8 u8 @ [0, 12582912)  (dead after k3c)
    //   Xt  u16 @ [12582912, 37748736)  (dead after k2)
    // ws (28.4 MB): Ks8/Vs8 u8 (-> reused as Y bf16 after k3a), KVraw, KVs, Wlv
    float* out0 = (float*)d_out;
    float* out1 = out0 + 12582912;
    char*  ob   = (char*)d_out;
    u8*    Qs8  = (u8*)ob;
    u16*   Xt   = (u16*)(ob + 12582912);
    char*  ws   = (char*)d_ws;
    u8*    Ks8  = (u8*)ws;
    u8*    Vs8  = (u8*)ws + 12582912;
    u16*   Yb   = (u16*)ws;                      // reuse Ks8+Vs8 after k3a
    float* KVraw = (float*)(ws + 25165824);      // 196608 B
    u16*   KVs   = (u16*)(ws + 25362432);        // 98304 B
    u16*   Wlv   = (u16*)(ws + 25460736);        // 2949120 B

    hipLaunchKernelGGL(prep, dim3(1344), dim3(256), 0, stream, x, Xt, qw, kw, vw, pw, Wlv, KVraw);
    hipLaunchKernelGGL(k2, dim3(256, 3, 3), dim3(256), 0, stream,
                       Xt, Wlv,
                       qg, qb, qm, qv,
                       kg, kb, km, kv,
                       vg, vb, vm, vv,
                       Qs8, Ks8, Vs8, out1);
    hipLaunchKernelGGL(k3a, dim3(8, 32), dim3(96, 4), 0, stream, Ks8, Vs8, KVraw);
    hipLaunchKernelGGL(k3b, dim3(32), dim3(384), 0, stream, KVraw, KVs);
    hipLaunchKernelGGL(k3c, dim3(6144), dim3(256), 0, stream, Qs8, KVs, Yb);
    hipLaunchKernelGGL(k4, dim3(256, 3), dim3(256), 0, stream,
                       Yb, Wlv + 9 * 147456, pb, pg, pbe, pm, pv, x, out0);
}

// Round 2
// 342.854 us; speedup vs baseline: 1.0138x; 1.0138x over previous
//
#include <hip/hip_runtime.h>

typedef unsigned short u16;
typedef unsigned char u8;
typedef __bf16 bf16x8 __attribute__((ext_vector_type(8)));
typedef float f32x4 __attribute__((ext_vector_type(4)));
typedef float f32x16 __attribute__((ext_vector_type(16)));
typedef u16 u16x8 __attribute__((ext_vector_type(8)));

__device__ __forceinline__ float bf2f(u16 u) {
    union { unsigned i; float f; } c; c.i = ((unsigned)u) << 16; return c.f;
}
__device__ __forceinline__ u16 f2bf(float f) {
    union { float f; unsigned i; } c; c.f = f;
    unsigned r = c.i + 0x7FFFu + ((c.i >> 16) & 1u);
    return (u16)(r >> 16);
}

// async global->LDS, 16B per lane (global_load_lds_dwordx4)
__device__ __forceinline__ void gload16(const void* g, void* l) {
    __builtin_amdgcn_global_load_lds(
        (const __attribute__((address_space(1))) void*)g,
        (__attribute__((address_space(3))) void*)l, 16, 0, 0);
}

// ---------- PREP: fused [k1: shortcut LIF + transpose] + [weight levels] + [KVraw zero] ----------
// grid: 768 k1-blocks (3 c-tiles x 8 n-tiles x 32 b) + 576 weight blocks; block 256
__global__ __launch_bounds__(256) void prep(const float* __restrict__ X, u16* __restrict__ Xt,
    const float* __restrict__ qw, const float* __restrict__ kw,
    const float* __restrict__ vw, const float* __restrict__ pw,
    u16* __restrict__ W, float* __restrict__ KVraw) {
    const int bid = blockIdx.x;
    if (bid < 768) {
        // LDS layout [t][n][c] so the transpose READ is a single ds_read_b128 (conflict-free);
        // writes are scalar u16 at 272B row stride (2-way = free).
        __shared__ __attribute__((aligned(16))) u16 s2[4][32][136];
        const int c0 = (bid % 3) * 128;
        const int n0 = ((bid / 3) & 7) * 32;
        const int b = bid / 24;
        const int n_l = threadIdx.x & 31, cg = threadIdx.x >> 5;
        for (int jj = 0; jj < 16; jj++) {
            int c_l = cg + jj * 8;
            float vm = 0.f;
            #pragma unroll
            for (int t = 0; t < 4; t++) {
                float xv = X[(((long)t * 32 + b) * 384 + c0 + c_l) * 256 + n0 + n_l];
                vm += (xv - vm) * 0.5f;
                u16 sp = 0;
                if (vm >= 1.0f) { sp = 0x3F80u; vm = 0.f; }
                s2[t][n_l][c_l] = sp;
            }
        }
        __syncthreads();
        const int c8 = (threadIdx.x & 15) << 3;
        const int ng = threadIdx.x >> 4;
        for (int half = 0; half < 2; half++) {
            int n = ng + half * 16;
            #pragma unroll
            for (int t = 0; t < 4; t++) {
                u16x8 v = *(const u16x8*)&s2[t][n][c8];
                *(u16x8*)&Xt[(((long)b * 256 + n0 + n) * 4 + t) * 384 + c0 + c8] = v;
            }
        }
    } else {
        const int idx = (bid - 768) * 256 + threadIdx.x;   // [0, 147456)
        const float* srcs[3] = {qw, kw, vw};
        #pragma unroll
        for (int m = 0; m < 3; m++) {
            float w = srcs[m][idx];
            u16 h0 = f2bf(w);  float r1 = w - bf2f(h0);
            u16 h1 = f2bf(r1); float r2 = r1 - bf2f(h1);
            u16 h2 = f2bf(r2);
            W[(m * 3 + 0) * 147456 + idx] = h0;
            W[(m * 3 + 1) * 147456 + idx] = h1;
            W[(m * 3 + 2) * 147456 + idx] = h2;
        }
        W[9 * 147456 + idx] = f2bf(pw[idx]);
        if (idx < 49152) KVraw[idx] = 0.f;
    }
}

// ---------- multi-level GEMM K-loop: 128x128 tile, BK=32, 32x32x16 MFMA, gload_lds + XOR swizzle ----------
// LDS: A tile [128][32] u16 at 0, B level p at (p+1)*4096 (u16 idx), linear dest byte = tid*16.
// Swizzle (rule #21, both-sides): LDS slot sigma of row r holds global 16B-slot sigma ^ ((r>>1)&3).
// Staging fetches inverse-swizzled global columns; fragment reads apply the same XOR.
template<int NL>
__device__ __forceinline__ void gemm32(const u16* __restrict__ A, const u16* __restrict__ B,
                                       long lstride, u16* lds, int m0, int n0, f32x16 (&acc)[2][2]) {
    const int tid = threadIdx.x, l = tid & 63, w = tid >> 6;
    const int wm = (w & 1) << 6, wn = (w >> 1) << 6;
    const int col = l & 31, kg = l >> 5;
    const int r0 = tid >> 2, sl = tid & 3, r1 = r0 + 64;
    const int cs0 = (sl ^ ((r0 >> 1) & 3)) << 3;
    const int cs1 = (sl ^ ((r1 >> 1) & 3)) << 3;
    const u16* Ap0 = A + (long)(m0 + r0) * 384 + cs0;
    const u16* Ap1 = A + (long)(m0 + r1) * 384 + cs1;
    const u16* Bp0 = B + (long)(n0 + r0) * 384 + cs0;
    const u16* Bp1 = B + (long)(n0 + r1) * 384 + cs1;
    u16* d0p = &lds[r0 * 32 + sl * 8];     // byte = tid*16 (wave-linear, required)
    u16* d1p = &lds[r1 * 32 + sl * 8];
    for (int kk = 0; kk < 384; kk += 32) {
        gload16(Ap0 + kk, d0p);
        gload16(Ap1 + kk, d1p);
        #pragma unroll
        for (int p = 0; p < NL; p++) {
            gload16(Bp0 + p * lstride + kk, d0p + (p + 1) * 4096);
            gload16(Bp1 + p * lstride + kk, d1p + (p + 1) * 4096);
        }
        __syncthreads();   // drains vmcnt(0): staged data visible
        #pragma unroll
        for (int c = 0; c < 2; c++) {
            bf16x8 af[2];
            #pragma unroll
            for (int i = 0; i < 2; i++) {
                int ra = wm + (i << 5) + col;
                int sa = ((2 * c + kg) ^ ((ra >> 1) & 3)) << 3;
                af[i] = *(const bf16x8*)&lds[ra * 32 + sa];
            }
            #pragma unroll
            for (int p = 0; p < NL; p++)
                #pragma unroll
                for (int j = 0; j < 2; j++) {
                    int rb = wn + (j << 5) + col;
                    int sb = ((2 * c + kg) ^ ((rb >> 1) & 3)) << 3;
                    bf16x8 bfr = *(const bf16x8*)&lds[(p + 1) * 4096 + rb * 32 + sb];
                    #pragma unroll
                    for (int i = 0; i < 2; i++)
                        acc[i][j] = __builtin_amdgcn_mfma_f32_32x32x16_bf16(af[i], bfr, acc[i][j], 0, 0, 0);
                }
        }
        __syncthreads();
    }
}

// ---------- K2: q/k/v conv1x1 (3-level split GEMM) + BN + LIF -> u8 spikes ----------
// 1D grid 2304, m-chunked per XCD: the 9 blocks (3 d-tiles x 3 branches) sharing an A-tile are
// consecutive within an XCD -> A-tile L2-resident across all 9 uses.
__global__ __launch_bounds__(256) void k2(
    const u16* __restrict__ Xt, const u16* __restrict__ Wlv,
    const float* __restrict__ g0, const float* __restrict__ b0, const float* __restrict__ m0_, const float* __restrict__ v0_,
    const float* __restrict__ g1, const float* __restrict__ b1, const float* __restrict__ m1_, const float* __restrict__ v1_,
    const float* __restrict__ g2, const float* __restrict__ b2, const float* __restrict__ m2_, const float* __restrict__ v2_,
    u8* __restrict__ oq, u8* __restrict__ ok, u8* __restrict__ ov, float* __restrict__ out1)
{
    __shared__ __attribute__((aligned(16))) u16 lds[17408];   // staging 32KB; epilogue tile 128x136 (34816B)
    const int bid = blockIdx.x;
    const int xcd = bid & 7, bi = bid >> 3;
    const int mt = (bi / 9) * 8 + xcd;
    const int sub = bi % 9;
    const int m0 = mt * 128, d0 = (sub % 3) * 128, br = sub / 3;
    const float* G  = br == 0 ? g0  : (br == 1 ? g1  : g2);
    const float* Be = br == 0 ? b0  : (br == 1 ? b1  : b2);
    const float* Mu = br == 0 ? m0_ : (br == 1 ? m1_ : m2_);
    const float* Va = br == 0 ? v0_ : (br == 1 ? v1_ : v2_);

    f32x16 acc[2][2];
    #pragma unroll
    for (int i = 0; i < 2; i++)
        #pragma unroll
        for (int j = 0; j < 2; j++)
            #pragma unroll
            for (int r = 0; r < 16; r++) acc[i][j][r] = 0.f;
    gemm32<3>(Xt, Wlv + (long)br * 3 * 147456, 147456L, lds, m0, d0, acc);

    const int tid = threadIdx.x, l = tid & 63, w = tid >> 6;
    const int wm = (w & 1) << 6, wn = (w >> 1) << 6;
    const int col = l & 31;
    float sc[2], mu[2], be[2];
    #pragma unroll
    for (int j = 0; j < 2; j++) {
        int d = d0 + wn + (j << 5) + col;
        sc[j] = G[d] / sqrtf(Va[d] + 1e-5f);
        mu[j] = Mu[d];
        be[j] = Be[d];
    }
    // 32x32 C/D: col = l&31, row = (reg&3) + 8*(reg>>2) + 4*(l>>5); reg&3 == t (LIF in-register)
    u16* tile = lds;
    #pragma unroll
    for (int i = 0; i < 2; i++)
        #pragma unroll
        for (int j = 0; j < 2; j++)
            #pragma unroll
            for (int q = 0; q < 4; q++) {
                float vm = 0.f;
                int mb = wm + (i << 5) + (q << 3) + ((l >> 5) << 2);
                #pragma unroll
                for (int t = 0; t < 4; t++) {
                    float bn = (acc[i][j][q * 4 + t] - mu[j]) * sc[j] + be[j];
                    vm += (bn - vm) * 0.5f;
                    u16 s = 0;
                    if (vm >= 1.0f) { s = 0x3F80u; vm = 0.f; }
                    tile[(mb + t) * 136 + wn + (j << 5) + col] = s;
                }
            }
    __syncthreads();
    const int c8 = (tid & 15) << 3;
    u8* Out8 = br == 0 ? oq : (br == 1 ? ok : ov);
    #pragma unroll
    for (int p = 0; p < 8; p++) {
        int ml = (tid >> 4) + (p << 4);
        u16x8 sp = *(const u16x8*)&tile[ml * 136 + c8];
        union { u8 b[8]; uint2 u; } pk;
        #pragma unroll
        for (int r = 0; r < 8; r++) pk.b[r] = sp[r] ? 1 : 0;
        *(uint2*)&Out8[(long)(m0 + ml) * 384 + d0 + c8] = pk.u;
    }
    if (br == 2) {   // output 1: v spikes as f32 in (T,B,h,N,Ch)
        const int b = m0 >> 10, n_base = (m0 >> 2) & 255;
        const int dl = tid & 127, d = d0 + dl;
        const int h = d / 48, ch = d % 48;
        for (int q = 0; q < 64; q++) {
            int ml = (tid >> 7) + (q << 1);
            int t = ml & 3, n = n_base + (ml >> 2);
            out1[((((long)t * 32 + b) * 8 + h) * 256 + n) * 48 + ch] =
                tile[ml * 136 + dl] ? 1.0f : 0.f;
        }
    }
}

// ---------- K3a: kv partial counts (exact int), uchar4 loads ----------
// block (96,4): tidx = d-quad, tidy = t; grid (8 n-chunks, 32 b)
__global__ __launch_bounds__(384) void k3a(const u8* __restrict__ Ks, const u8* __restrict__ Vs,
                                           float* __restrict__ kv_raw) {
    const int b = blockIdx.y, nc = blockIdx.x;
    const int d4 = threadIdx.x * 4, t = threadIdx.y;
    int cnt0 = 0, cnt1 = 0, cnt2 = 0, cnt3 = 0;
    for (int nl = 0; nl < 32; nl++) {
        const long row = ((long)b * 256 + nc * 32 + nl) * 4 + t;
        uchar4 kk = *(const uchar4*)&Ks[row * 384 + d4];
        uchar4 vv = *(const uchar4*)&Vs[row * 384 + d4];
        cnt0 += (kk.x & vv.x); cnt1 += (kk.y & vv.y);
        cnt2 += (kk.z & vv.z); cnt3 += (kk.w & vv.w);
    }
    float* dst = &kv_raw[((long)t * 32 + b) * 384 + d4];
    atomicAdd(dst + 0, (float)cnt0);
    atomicAdd(dst + 1, (float)cnt1);
    atomicAdd(dst + 2, (float)cnt2);
    atomicAdd(dst + 3, (float)cnt3);
}

// ---------- K3b: LIF(kv, v_th=0.5) ----------
__global__ __launch_bounds__(384) void k3b(const float* __restrict__ kv_raw, u16* __restrict__ kvs) {
    const int b = blockIdx.x, d = threadIdx.x;
    float vm = 0.f;
    #pragma unroll
    for (int t = 0; t < 4; t++) {
        vm += (kv_raw[((long)t * 32 + b) * 384 + d] - vm) * 0.5f;
        u16 sp = 0;
        if (vm >= 0.5f) { sp = 0x3F80u; vm = 0.f; }
        kvs[((long)t * 32 + b) * 384 + d] = sp;
    }
}

// ---------- K3c: Y(bf16) = q(u8) * KV(bf16 mask) ----------
__global__ __launch_bounds__(256) void k3c(const u8* __restrict__ Qs, const u16* __restrict__ KVs,
                                           u16* __restrict__ Y) {
    const long i8 = ((long)blockIdx.x * 256 + threadIdx.x) * 8;
    const int m = (int)(i8 / 384), d8 = (int)(i8 % 384);
    const int t = m & 3, b = m >> 10;
    uint2 q8 = *(const uint2*)(Qs + i8);
    const u8* qb = (const u8*)&q8;
    u16x8 kv = *(const u16x8*)(KVs + ((long)(t * 32 + b) * 384 + d8));
    u16x8 y;
    #pragma unroll
    for (int j = 0; j < 8; j++) y[j] = qb[j] ? kv[j] : (u16)0;
    *(u16x8*)(Y + i8) = y;
}

// ---------- K4: proj GEMM + bias + BN + identity -> f32 (T,B,C,H,W) ----------
__global__ __launch_bounds__(256) void k4(
    const u16* __restrict__ Y, const u16* __restrict__ PW,
    const float* __restrict__ PB, const float* __restrict__ PG, const float* __restrict__ PBe,
    const float* __restrict__ PM, const float* __restrict__ PV,
    const float* __restrict__ X, float* __restrict__ O)
{
    __shared__ __attribute__((aligned(16))) u16 lds[17408];
    const int bid = blockIdx.x;
    const int xcd = bid & 7, bi = bid >> 3;
    const int mt = (bi / 3) * 8 + xcd;
    const int m0 = mt * 128, e0 = (bi % 3) * 128;
    f32x16 acc[2][2];
    #pragma unroll
    for (int i = 0; i < 2; i++)
        #pragma unroll
        for (int j = 0; j < 2; j++)
            #pragma unroll
            for (int r = 0; r < 16; r++) acc[i][j][r] = 0.f;
    gemm32<1>(Y, PW, 0L, lds, m0, e0, acc);

    const int tid = threadIdx.x, l = tid & 63, w = tid >> 6;
    const int wm = (w & 1) << 6, wn = (w >> 1) << 6;
    const int col = l & 31;
    float sc[2], mu[2], be[2], pb[2];
    #pragma unroll
    for (int j = 0; j < 2; j++) {
        int e = e0 + wn + (j << 5) + col;
        sc[j] = PG[e] / sqrtf(PV[e] + 1e-5f);
        mu[j] = PM[e];
        be[j] = PBe[e];
        pb[j] = PB[e];
    }
    float* smemf = (float*)lds;   // 64x136 f32 tile = 34816 B
    const int b = m0 >> 10, n_base = (m0 >> 2) & 255;
    for (int cchunk = 0; cchunk < 2; cchunk++) {
        if ((w & 1) == cchunk) {
            #pragma unroll
            for (int i = 0; i < 2; i++)
                #pragma unroll
                for (int j = 0; j < 2; j++)
                    #pragma unroll
                    for (int q = 0; q < 4; q++)
                        #pragma unroll
                        for (int t = 0; t < 4; t++) {
                            float z = (acc[i][j][q * 4 + t] + pb[j] - mu[j]) * sc[j] + be[j];
                            smemf[((i << 5) + (q << 3) + ((l >> 5) << 2) + t) * 136 + wn + (j << 5) + col] = z;
                        }
        }
        __syncthreads();
        const int n_l = tid & 15, eg = tid >> 4;
        #pragma unroll
        for (int ee = 0; ee < 8; ee++) {
            int e_l = eg + (ee << 4);
            #pragma unroll
            for (int t = 0; t < 4; t++) {
                float z = smemf[((n_l << 2) + t) * 136 + e_l];
                long gi = (((long)t * 32 + b) * 384 + e0 + e_l) * 256 + n_base + (cchunk << 4) + n_l;
                O[gi] = z + X[gi];
            }
        }
        __syncthreads();
    }
}

extern "C" void kernel_launch(void* const* d_in, const int* in_sizes, int n_in,
                              void* d_out, int out_size, void* d_ws, size_t ws_size,
                              hipStream_t stream) {
    (void)in_sizes; (void)n_in; (void)out_size; (void)ws_size;
    const float* x   = (const float*)d_in[0];
    const float* qw  = (const float*)d_in[1];
    const float* qg  = (const float*)d_in[2];
    const float* qb  = (const float*)d_in[3];
    const float* qm  = (const float*)d_in[4];
    const float* qv  = (const float*)d_in[5];
    const float* kw  = (const float*)d_in[6];
    const float* kg  = (const float*)d_in[7];
    const float* kb  = (const float*)d_in[8];
    const float* km  = (const float*)d_in[9];
    const float* kv  = (const float*)d_in[10];
    const float* vw  = (const float*)d_in[11];
    const float* vg  = (const float*)d_in[12];
    const float* vb  = (const float*)d_in[13];
    const float* vm  = (const float*)d_in[14];
    const float* vv  = (const float*)d_in[15];
    const float* pw  = (const float*)d_in[16];
    const float* pb  = (const float*)d_in[17];
    const float* pg  = (const float*)d_in[18];
    const float* pbe = (const float*)d_in[19];
    const float* pm  = (const float*)d_in[20];
    const float* pv  = (const float*)d_in[21];

    // out0 (50.3 MB) as scratch until k4 writes it:
    //   Qs8 u8 @ [0, 12582912)  (dead after k3c)
    //   Xt  u16 @ [12582912, 37748736)  (dead after k2)
    // ws (28.4 MB): Ks8/Vs8 u8 (-> reused as Y bf16 after k3a), KVraw, KVs, Wlv
    float* out0 = (float*)d_out;
    float* out1 = out0 + 12582912;
    char*  ob   = (char*)d_out;
    u8*    Qs8  = (u8*)ob;
    u16*   Xt   = (u16*)(ob + 12582912);
    char*  ws   = (char*)d_ws;
    u8*    Ks8  = (u8*)ws;
    u8*    Vs8  = (u8*)ws + 12582912;
    u16*   Yb   = (u16*)ws;                      // reuse Ks8+Vs8 after k3a
    float* KVraw = (float*)(ws + 25165824);      // 196608 B
    u16*   KVs   = (u16*)(ws + 25362432);        // 98304 B
    u16*   Wlv   = (u16*)(ws + 25460736);        // 2949120 B

    hipLaunchKernelGGL(prep, dim3(1344), dim3(256), 0, stream, x, Xt, qw, kw, vw, pw, Wlv, KVraw);
    hipLaunchKernelGGL(k2, dim3(2304), dim3(256), 0, stream,
                       Xt, Wlv,
                       qg, qb, qm, qv,
                       kg, kb, km, kv,
                       vg, vb, vm, vv,
                       Qs8, Ks8, Vs8, out1);
    hipLaunchKernelGGL(k3a, dim3(8, 32), dim3(96, 4), 0, stream, Ks8, Vs8, KVraw);
    hipLaunchKernelGGL(k3b, dim3(32), dim3(384), 0, stream, KVraw, KVs);
    hipLaunchKernelGGL(k3c, dim3(6144), dim3(256), 0, stream, Qs8, KVs, Yb);
    hipLaunchKernelGGL(k4, dim3(768), dim3(256), 0, stream,
                       Yb, Wlv + 9 * 147456, pb, pg, pbe, pm, pv, x, out0);
}

// Round 3
// 320.834 us; speedup vs baseline: 1.0834x; 1.0686x over previous
//
#include <hip/hip_runtime.h>

typedef unsigned short u16;
typedef unsigned char u8;
typedef signed char i8;
typedef int i32x4 __attribute__((ext_vector_type(4)));
typedef int i32x16 __attribute__((ext_vector_type(16)));
typedef u16 u16x8 __attribute__((ext_vector_type(8)));
typedef u8 u8x16 __attribute__((ext_vector_type(16)));

// async global->LDS, 16B per lane (global_load_lds_dwordx4)
__device__ __forceinline__ void gload16(const void* g, void* l) {
    __builtin_amdgcn_global_load_lds(
        (const __attribute__((address_space(1))) void*)g,
        (__attribute__((address_space(3))) void*)l, 16, 0, 0);
}

// ---------- PREP: fused [k1: shortcut LIF + transpose -> u8] + [i8 weight levels + row scales] ----------
// grid: 768 k1-blocks (3 c-tiles x 8 n-tiles x 32 b) + 384 weight blocks (1 row/wave); block 256
__global__ __launch_bounds__(256) void prep(const float* __restrict__ X, u8* __restrict__ Xt,
    const float* __restrict__ qw, const float* __restrict__ kw,
    const float* __restrict__ vw, const float* __restrict__ pw,
    i8* __restrict__ Wq, float* __restrict__ Sc, float* __restrict__ KVraw) {
    const int bid = blockIdx.x;
    if (bid < 768) {
        // LDS [t][n][c] u8 so the transpose READ is one 16B vector load
        __shared__ __attribute__((aligned(16))) u8 s2[4][32][136];
        const int c0 = (bid % 3) * 128;
        const int n0 = ((bid / 3) & 7) * 32;
        const int b = bid / 24;
        const int n_l = threadIdx.x & 31, cg = threadIdx.x >> 5;
        for (int jj = 0; jj < 16; jj++) {
            int c_l = cg + jj * 8;
            float vm = 0.f;
            #pragma unroll
            for (int t = 0; t < 4; t++) {
                float xv = X[(((long)t * 32 + b) * 384 + c0 + c_l) * 256 + n0 + n_l];
                vm += (xv - vm) * 0.5f;
                u8 sp = 0;
                if (vm >= 1.0f) { sp = 1; vm = 0.f; }
                s2[t][n_l][c_l] = sp;
            }
        }
        __syncthreads();
        const int c16 = (threadIdx.x & 7) << 4;       // 8 lanes x 16B = 128 c
        const int n = (threadIdx.x >> 3) & 31;
        #pragma unroll
        for (int t = 0; t < 4; t++) {
            u8x16 v = *(const u8x16*)&s2[t][n][c16];
            *(u8x16*)&Xt[(((long)b * 256 + n0 + n) * 4 + t) * 384 + c0 + c16] = v;
        }
    } else {
        // i8 3-level (qkv) / 2-level (proj) quantization, one 384-wide row per wave
        const int wv = bid - 768;                     // 0..383
        const int w = threadIdx.x >> 6, lane = threadIdx.x & 63;
        const int r = wv * 4 + w;                     // 0..1535
        const int m = r / 384, d = r - m * 384;
        const float* srcs[4] = {qw, kw, vw, pw};
        const float* row = srcs[m] + (long)d * 384;
        float a[6]; float mx = 0.f;
        #pragma unroll
        for (int jj = 0; jj < 6; jj++) { a[jj] = row[lane + (jj << 6)]; mx = fmaxf(mx, fabsf(a[jj])); }
        #pragma unroll
        for (int off = 1; off < 64; off <<= 1) mx = fmaxf(mx, __shfl_xor(mx, off));
        float scale = mx * (1.f / 127.f);
        float sinv = mx > 0.f ? 127.f / mx : 0.f;
        if (lane == 0) Sc[r] = scale;
        i8* dst0 = Wq + (long)(m == 3 ? 9 : m * 3) * 147456 + (long)d * 384;
        #pragma unroll
        for (int jj = 0; jj < 6; jj++) {
            float x = a[jj] * sinv;
            float q1 = rintf(x);         float r1 = x - q1;
            float q2 = rintf(r1 * 128.f); float r2 = r1 * 128.f - q2;
            float q3 = rintf(r2 * 128.f);
            int c = lane + (jj << 6);
            dst0[c] = (i8)(int)q1;
            dst0[147456 + c] = (i8)(int)q2;
            if (m != 3) dst0[2 * 147456 + c] = (i8)(int)q3;
        }
        const int idx = wv * 256 + threadIdx.x;
        if (idx < 49152) KVraw[idx] = 0.f;
    }
}

// ---------- i8 multi-level GEMM: 128x128 tile, BK=64, mfma_i32_32x32x32_i8, gload_lds + XOR swizzle ----------
// LDS: A tile [128][64] i8 at 0, B level p at (p+1)*8192; dest byte = tid*16 (wave-linear).
// Swizzle: LDS 16B-slot s of row r holds global slot s ^ ((r>>1)&3); reads apply the same XOR.
template<int NL>
__device__ __forceinline__ void gemm_i8(const u8* __restrict__ A, const i8* __restrict__ B,
                                        long lstride, char* lds8, int m0, int n0, i32x16 (&acc)[NL][2][2]) {
    const int tid = threadIdx.x, l = tid & 63, w = tid >> 6;
    const int wm = (w & 1) << 6, wn = (w >> 1) << 6;
    const int col = l & 31, kg = l >> 5;
    const int r0 = tid >> 2, sl = tid & 3, r1 = r0 + 64;
    const int cs0 = (sl ^ ((r0 >> 1) & 3)) << 4;
    const int cs1 = (sl ^ ((r1 >> 1) & 3)) << 4;
    const u8* Ap0 = A + (long)(m0 + r0) * 384 + cs0;
    const u8* Ap1 = A + (long)(m0 + r1) * 384 + cs1;
    const i8* Bp0 = B + (long)(n0 + r0) * 384 + cs0;
    const i8* Bp1 = B + (long)(n0 + r1) * 384 + cs1;
    char* d0p = lds8 + r0 * 64 + sl * 16;     // byte = tid*16
    char* d1p = lds8 + r1 * 64 + sl * 16;
    for (int kk = 0; kk < 384; kk += 64) {
        gload16(Ap0 + kk, d0p);
        gload16(Ap1 + kk, d1p);
        #pragma unroll
        for (int p = 0; p < NL; p++) {
            gload16(Bp0 + p * lstride + kk, d0p + (p + 1) * 8192);
            gload16(Bp1 + p * lstride + kk, d1p + (p + 1) * 8192);
        }
        __syncthreads();   // drains vmcnt(0): staged data visible
        #pragma unroll
        for (int c = 0; c < 2; c++) {
            i32x4 af[2];
            #pragma unroll
            for (int i = 0; i < 2; i++) {
                int ra = wm + (i << 5) + col;
                int sa = ((2 * c + kg) ^ ((ra >> 1) & 3)) << 4;
                af[i] = *(const i32x4*)(lds8 + ra * 64 + sa);
            }
            #pragma unroll
            for (int p = 0; p < NL; p++)
                #pragma unroll
                for (int j = 0; j < 2; j++) {
                    int rb = wn + (j << 5) + col;
                    int sb = ((2 * c + kg) ^ ((rb >> 1) & 3)) << 4;
                    i32x4 bfr = *(const i32x4*)(lds8 + (p + 1) * 8192 + rb * 64 + sb);
                    #pragma unroll
                    for (int i = 0; i < 2; i++)
                        acc[p][i][j] = __builtin_amdgcn_mfma_i32_32x32x32_i8(af[i], bfr, acc[p][i][j], 0, 0, 0);
                }
        }
        __syncthreads();
    }
}

// ---------- K2: q/k/v conv1x1 (3-level i8 GEMM) + scale + BN + LIF -> u8 spikes ----------
__global__ __launch_bounds__(256) void k2(
    const u8* __restrict__ Xt, const i8* __restrict__ Wq, const float* __restrict__ Sc,
    const float* __restrict__ g0, const float* __restrict__ b0, const float* __restrict__ m0_, const float* __restrict__ v0_,
    const float* __restrict__ g1, const float* __restrict__ b1, const float* __restrict__ m1_, const float* __restrict__ v1_,
    const float* __restrict__ g2, const float* __restrict__ b2, const float* __restrict__ m2_, const float* __restrict__ v2_,
    u8* __restrict__ oq, u8* __restrict__ ok, u8* __restrict__ ov, float* __restrict__ out1)
{
    __shared__ __attribute__((aligned(16))) char lds8[32768];   // staging 32KB; epilogue tile 128x144 u8 (18432B)
    const int bid = blockIdx.x;
    const int xcd = bid & 7, bi = bid >> 3;
    const int mt = (bi / 9) * 8 + xcd;
    const int sub = bi % 9;
    const int m0 = mt * 128, d0 = (sub % 3) * 128, br = sub / 3;
    const float* G  = br == 0 ? g0  : (br == 1 ? g1  : g2);
    const float* Be = br == 0 ? b0  : (br == 1 ? b1  : b2);
    const float* Mu = br == 0 ? m0_ : (br == 1 ? m1_ : m2_);
    const float* Va = br == 0 ? v0_ : (br == 1 ? v1_ : v2_);

    i32x16 acc[3][2][2];
    #pragma unroll
    for (int p = 0; p < 3; p++)
        #pragma unroll
        for (int i = 0; i < 2; i++)
            #pragma unroll
            for (int j = 0; j < 2; j++)
                #pragma unroll
                for (int r = 0; r < 16; r++) acc[p][i][j][r] = 0;
    gemm_i8<3>(Xt, Wq + (long)br * 3 * 147456, 147456L, lds8, m0, d0, acc);

    const int tid = threadIdx.x, l = tid & 63, w = tid >> 6;
    const int wm = (w & 1) << 6, wn = (w >> 1) << 6;
    const int col = l & 31;
    float scb[2], mu[2], be[2], wsc[2];
    #pragma unroll
    for (int j = 0; j < 2; j++) {
        int d = d0 + wn + (j << 5) + col;
        scb[j] = G[d] / sqrtf(Va[d] + 1e-5f);
        mu[j] = Mu[d];
        be[j] = Be[d];
        wsc[j] = Sc[br * 384 + d];
    }
    u8* tile8 = (u8*)lds8;   // stride 144
    const float c1 = 0.0078125f, c2 = 6.103515625e-05f;
    #pragma unroll
    for (int i = 0; i < 2; i++)
        #pragma unroll
        for (int j = 0; j < 2; j++)
            #pragma unroll
            for (int q = 0; q < 4; q++) {
                float vm = 0.f;
                int mb = wm + (i << 5) + (q << 3) + ((l >> 5) << 2);
                #pragma unroll
                for (int t = 0; t < 4; t++) {
                    int reg = q * 4 + t;
                    float f = (float)acc[0][i][j][reg] + (float)acc[1][i][j][reg] * c1
                            + (float)acc[2][i][j][reg] * c2;
                    float bn = (f * wsc[j] - mu[j]) * scb[j] + be[j];
                    vm += (bn - vm) * 0.5f;
                    u8 s = 0;
                    if (vm >= 1.0f) { s = 1; vm = 0.f; }
                    tile8[(mb + t) * 144 + wn + (j << 5) + col] = s;
                }
            }
    __syncthreads();
    const int c8 = (tid & 15) << 3;
    u8* Out8 = br == 0 ? oq : (br == 1 ? ok : ov);
    #pragma unroll
    for (int p = 0; p < 8; p++) {
        int ml = (tid >> 4) + (p << 4);
        *(uint2*)&Out8[(long)(m0 + ml) * 384 + d0 + c8] = *(const uint2*)&tile8[ml * 144 + c8];
    }
    if (br == 2) {   // output 1: v spikes as f32 in (T,B,h,N,Ch)
        const int b = m0 >> 10, n_base = (m0 >> 2) & 255;
        const int dl = tid & 127, d = d0 + dl;
        const int h = d / 48, ch = d % 48;
        for (int q = 0; q < 64; q++) {
            int ml = (tid >> 7) + (q << 1);
            int t = ml & 3, n = n_base + (ml >> 2);
            out1[((((long)t * 32 + b) * 8 + h) * 256 + n) * 48 + ch] =
                tile8[ml * 144 + dl] ? 1.0f : 0.f;
        }
    }
}

// ---------- K3a: kv partial counts (exact int), uchar4 loads ----------
__global__ __launch_bounds__(384) void k3a(const u8* __restrict__ Ks, const u8* __restrict__ Vs,
                                           float* __restrict__ kv_raw) {
    const int b = blockIdx.y, nc = blockIdx.x;
    const int d4 = threadIdx.x * 4, t = threadIdx.y;
    int cnt0 = 0, cnt1 = 0, cnt2 = 0, cnt3 = 0;
    for (int nl = 0; nl < 32; nl++) {
        const long row = ((long)b * 256 + nc * 32 + nl) * 4 + t;
        uchar4 kk = *(const uchar4*)&Ks[row * 384 + d4];
        uchar4 vv = *(const uchar4*)&Vs[row * 384 + d4];
        cnt0 += (kk.x & vv.x); cnt1 += (kk.y & vv.y);
        cnt2 += (kk.z & vv.z); cnt3 += (kk.w & vv.w);
    }
    float* dst = &kv_raw[((long)t * 32 + b) * 384 + d4];
    atomicAdd(dst + 0, (float)cnt0);
    atomicAdd(dst + 1, (float)cnt1);
    atomicAdd(dst + 2, (float)cnt2);
    atomicAdd(dst + 3, (float)cnt3);
}

// ---------- K3b: LIF(kv, v_th=0.5) -> u8 ----------
__global__ __launch_bounds__(384) void k3b(const float* __restrict__ kv_raw, u8* __restrict__ kvs) {
    const int b = blockIdx.x, d = threadIdx.x;
    float vm = 0.f;
    #pragma unroll
    for (int t = 0; t < 4; t++) {
        vm += (kv_raw[((long)t * 32 + b) * 384 + d] - vm) * 0.5f;
        u8 sp = 0;
        if (vm >= 0.5f) { sp = 1; vm = 0.f; }
        kvs[((long)t * 32 + b) * 384 + d] = sp;
    }
}

// ---------- K3c: Y(u8) = q(u8) & KV(u8), 16B per thread ----------
__global__ __launch_bounds__(256) void k3c(const u8* __restrict__ Qs, const u8* __restrict__ KVs,
                                           u8* __restrict__ Y) {
    const long i16 = ((long)blockIdx.x * 256 + threadIdx.x) * 16;
    const int m = (int)(i16 / 384), d16 = (int)(i16 % 384);
    const int t = m & 3, b = m >> 10;
    uint4 q = *(const uint4*)(Qs + i16);
    uint4 kvv = *(const uint4*)(KVs + ((long)(t * 32 + b) * 384 + d16));
    uint4 y;
    y.x = q.x & kvv.x; y.y = q.y & kvv.y; y.z = q.z & kvv.z; y.w = q.w & kvv.w;
    *(uint4*)(Y + i16) = y;
}

// ---------- K4: proj GEMM (2-level i8) + bias + BN + identity -> f32 (T,B,C,H,W) ----------
__global__ __launch_bounds__(256) void k4(
    const u8* __restrict__ Y, const i8* __restrict__ Pq, const float* __restrict__ Scp,
    const float* __restrict__ PB, const float* __restrict__ PG, const float* __restrict__ PBe,
    const float* __restrict__ PM, const float* __restrict__ PV,
    const float* __restrict__ X, float* __restrict__ O)
{
    __shared__ __attribute__((aligned(16))) char lds8[35072];  // staging 24576; f32 tile 64x137 (35072B)
    const int bid = blockIdx.x;
    const int xcd = bid & 7, bi = bid >> 3;
    const int mt = (bi / 3) * 8 + xcd;
    const int m0 = mt * 128, e0 = (bi % 3) * 128;
    i32x16 acc[2][2][2];
    #pragma unroll
    for (int p = 0; p < 2; p++)
        #pragma unroll
        for (int i = 0; i < 2; i++)
            #pragma unroll
            for (int j = 0; j < 2; j++)
                #pragma unroll
                for (int r = 0; r < 16; r++) acc[p][i][j][r] = 0;
    gemm_i8<2>(Y, Pq, 147456L, lds8, m0, e0, acc);

    const int tid = threadIdx.x, l = tid & 63, w = tid >> 6;
    const int wm = (w & 1) << 6, wn = (w >> 1) << 6;
    const int col = l & 31;
    float scb[2], mu[2], be[2], pbb[2], wsc[2];
    #pragma unroll
    for (int j = 0; j < 2; j++) {
        int e = e0 + wn + (j << 5) + col;
        scb[j] = PG[e] / sqrtf(PV[e] + 1e-5f);
        mu[j] = PM[e];
        be[j] = PBe[e];
        pbb[j] = PB[e];
        wsc[j] = Scp[e];
    }
    float* smemf = (float*)lds8;   // stride 137
    const int b = m0 >> 10, n_base = (m0 >> 2) & 255;
    const float c1 = 0.0078125f;
    for (int cchunk = 0; cchunk < 2; cchunk++) {
        if ((w & 1) == cchunk) {
            #pragma unroll
            for (int i = 0; i < 2; i++)
                #pragma unroll
                for (int j = 0; j < 2; j++)
                    #pragma unroll
                    for (int q = 0; q < 4; q++)
                        #pragma unroll
                        for (int t = 0; t < 4; t++) {
                            int reg = q * 4 + t;
                            float f = (float)acc[0][i][j][reg] + (float)acc[1][i][j][reg] * c1;
                            float z = (f * wsc[j] + pbb[j] - mu[j]) * scb[j] + be[j];
                            smemf[((i << 5) + (q << 3) + ((l >> 5) << 2) + t) * 137 + wn + (j << 5) + col] = z;
                        }
        }
        __syncthreads();
        const int n_l = tid & 15, eg = tid >> 4;
        #pragma unroll
        for (int ee = 0; ee < 8; ee++) {
            int e_l = eg + (ee << 4);
            #pragma unroll
            for (int t = 0; t < 4; t++) {
                float z = smemf[((n_l << 2) + t) * 137 + e_l];
                long gi = (((long)t * 32 + b) * 384 + e0 + e_l) * 256 + n_base + (cchunk << 4) + n_l;
                O[gi] = z + X[gi];
            }
        }
        __syncthreads();
    }
}

extern "C" void kernel_launch(void* const* d_in, const int* in_sizes, int n_in,
                              void* d_out, int out_size, void* d_ws, size_t ws_size,
                              hipStream_t stream) {
    (void)in_sizes; (void)n_in; (void)out_size; (void)ws_size;
    const float* x   = (const float*)d_in[0];
    const float* qw  = (const float*)d_in[1];
    const float* qg  = (const float*)d_in[2];
    const float* qb  = (const float*)d_in[3];
    const float* qm  = (const float*)d_in[4];
    const float* qv  = (const float*)d_in[5];
    const float* kw  = (const float*)d_in[6];
    const float* kg  = (const float*)d_in[7];
    const float* kb  = (const float*)d_in[8];
    const float* km  = (const float*)d_in[9];
    const float* kv  = (const float*)d_in[10];
    const float* vw  = (const float*)d_in[11];
    const float* vg  = (const float*)d_in[12];
    const float* vb  = (const float*)d_in[13];
    const float* vm  = (const float*)d_in[14];
    const float* vv  = (const float*)d_in[15];
    const float* pw  = (const float*)d_in[16];
    const float* pb  = (const float*)d_in[17];
    const float* pg  = (const float*)d_in[18];
    const float* pbe = (const float*)d_in[19];
    const float* pm  = (const float*)d_in[20];
    const float* pv  = (const float*)d_in[21];

    // out0 (50.3 MB) as scratch until k4 writes it:
    //   Qs8 u8 @ [0, 12582912)           (dead after k3c)
    //   Xt8 u8 @ [12582912, 25165824)    (dead after k2)
    // ws: Ks8/Vs8 u8 (-> reused as Y u8 after k3a), KVraw, kvs u8, Wq i8 (11 levels), Sc f32
    float* out0 = (float*)d_out;
    float* out1 = out0 + 12582912;
    char*  ob   = (char*)d_out;
    u8*    Qs8  = (u8*)ob;
    u8*    Xt8  = (u8*)(ob + 12582912);
    char*  ws   = (char*)d_ws;
    u8*    Ks8  = (u8*)ws;
    u8*    Vs8  = (u8*)ws + 12582912;
    u8*    Yb8  = (u8*)ws;                       // reuse Ks8 region after k3a
    float* KVraw = (float*)(ws + 25165824);      // 196608 B
    u8*    KVs8  = (u8*)(ws + 25362432);         // 49152 B
    i8*    Wq    = (i8*)(ws + 25411584);         // 11*147456 = 1622016 B
    float* Sc    = (float*)(ws + 27033600);      // 1536*4 = 6144 B

    hipLaunchKernelGGL(prep, dim3(1152), dim3(256), 0, stream, x, Xt8, qw, kw, vw, pw, Wq, Sc, KVraw);
    hipLaunchKernelGGL(k2, dim3(2304), dim3(256), 0, stream,
                       Xt8, Wq, Sc,
                       qg, qb, qm, qv,
                       kg, kb, km, kv,
                       vg, vb, vm, vv,
                       Qs8, Ks8, Vs8, out1);
    hipLaunchKernelGGL(k3a, dim3(8, 32), dim3(96, 4), 0, stream, Ks8, Vs8, KVraw);
    hipLaunchKernelGGL(k3b, dim3(32), dim3(384), 0, stream, KVraw, KVs8);
    hipLaunchKernelGGL(k3c, dim3(3072), dim3(256), 0, stream, Qs8, KVs8, Yb8);
    hipLaunchKernelGGL(k4, dim3(768), dim3(256), 0, stream,
                       Yb8, Wq + 9 * 147456L, Sc + 3 * 384, pb, pg, pbe, pm, pv, x, out0);
}

// Round 4
// 286.910 us; speedup vs baseline: 1.2115x; 1.1182x over previous
//
#include <hip/hip_runtime.h>

typedef unsigned short u16;
typedef unsigned char u8;
typedef signed char i8;
typedef int i32x4 __attribute__((ext_vector_type(4)));
typedef int i32x16 __attribute__((ext_vector_type(16)));
typedef float f32x4 __attribute__((ext_vector_type(4)));
typedef u16 u16x8 __attribute__((ext_vector_type(8)));
typedef u8 u8x16 __attribute__((ext_vector_type(16)));

// async global->LDS, 16B per lane (global_load_lds_dwordx4)
__device__ __forceinline__ void gload16(const void* g, void* l) {
    __builtin_amdgcn_global_load_lds(
        (const __attribute__((address_space(1))) void*)g,
        (__attribute__((address_space(3))) void*)l, 16, 0, 0);
}

// ---------- PREP: fused [k1: shortcut LIF + transpose -> u8] + [i8 weight levels + row scales] ----------
// grid: 768 k1-blocks (3 c-tiles x 8 n-tiles x 32 b) + 384 weight blocks (1 row/wave); block 256
__global__ __launch_bounds__(256) void prep(const float* __restrict__ X, u8* __restrict__ Xt,
    const float* __restrict__ qw, const float* __restrict__ kw,
    const float* __restrict__ vw, const float* __restrict__ pw,
    i8* __restrict__ Wq, float* __restrict__ Sc, float* __restrict__ KVraw) {
    const int bid = blockIdx.x;
    if (bid < 768) {
        // LDS [t][n][c] u8 so the transpose READ is one 16B vector load
        __shared__ __attribute__((aligned(16))) u8 s2[4][32][136];
        const int c0 = (bid % 3) * 128;
        const int n0 = ((bid / 3) & 7) * 32;
        const int b = bid / 24;
        const int n_l = threadIdx.x & 31, cg = threadIdx.x >> 5;
        for (int jj = 0; jj < 16; jj++) {
            int c_l = cg + jj * 8;
            float vm = 0.f;
            #pragma unroll
            for (int t = 0; t < 4; t++) {
                float xv = X[(((long)t * 32 + b) * 384 + c0 + c_l) * 256 + n0 + n_l];
                vm += (xv - vm) * 0.5f;
                u8 sp = 0;
                if (vm >= 1.0f) { sp = 1; vm = 0.f; }
                s2[t][n_l][c_l] = sp;
            }
        }
        __syncthreads();
        const int c16 = (threadIdx.x & 7) << 4;       // 8 lanes x 16B = 128 c
        const int n = (threadIdx.x >> 3) & 31;
        #pragma unroll
        for (int t = 0; t < 4; t++) {
            u8x16 v = *(const u8x16*)&s2[t][n][c16];
            *(u8x16*)&Xt[(((long)b * 256 + n0 + n) * 4 + t) * 384 + c0 + c16] = v;
        }
    } else {
        // i8 3-level (qkv) / 2-level (proj) quantization, one 384-wide row per wave
        const int wv = bid - 768;                     // 0..383
        const int w = threadIdx.x >> 6, lane = threadIdx.x & 63;
        const int r = wv * 4 + w;                     // 0..1535
        const int m = r / 384, d = r - m * 384;
        const float* srcs[4] = {qw, kw, vw, pw};
        const float* row = srcs[m] + (long)d * 384;
        float a[6]; float mx = 0.f;
        #pragma unroll
        for (int jj = 0; jj < 6; jj++) { a[jj] = row[lane + (jj << 6)]; mx = fmaxf(mx, fabsf(a[jj])); }
        #pragma unroll
        for (int off = 1; off < 64; off <<= 1) mx = fmaxf(mx, __shfl_xor(mx, off));
        float scale = mx * (1.f / 127.f);
        float sinv = mx > 0.f ? 127.f / mx : 0.f;
        if (lane == 0) Sc[r] = scale;
        i8* dst0 = Wq + (long)(m == 3 ? 9 : m * 3) * 147456 + (long)d * 384;
        #pragma unroll
        for (int jj = 0; jj < 6; jj++) {
            float x = a[jj] * sinv;
            float q1 = rintf(x);         float r1 = x - q1;
            float q2 = rintf(r1 * 128.f); float r2 = r1 * 128.f - q2;
            float q3 = rintf(r2 * 128.f);
            int c = lane + (jj << 6);
            dst0[c] = (i8)(int)q1;
            dst0[147456 + c] = (i8)(int)q2;
            if (m != 3) dst0[2 * 147456 + c] = (i8)(int)q3;
        }
        const int idx = wv * 256 + threadIdx.x;
        if (idx < 49152) KVraw[idx] = 0.f;
    }
}

// ---------- i8 multi-level GEMM: 128x64 tile, BK=64, mfma_i32_32x32x32_i8, gload_lds + XOR swizzle ----------
// LDS: A [128][64] i8 at 0 (8KB), B level p [64][64] at 8192 + p*4096 (4KB each).
// Staging dest byte = tid*16 (wave-linear, required). Swizzle: LDS 16B-slot s of row r holds
// global slot s ^ ((r>>1)&3); fragment reads apply the same XOR. cs(r) == cs(r+64).
// 4 waves in 2(M)x2(N): per-wave 64x32 output -> 32 acc regs per level (occupancy fix vs r3's 64).
template<int NL>
__device__ __forceinline__ void gemm_i8(const u8* __restrict__ A, const i8* __restrict__ B,
                                        long lstride, char* lds8, int m0, int n0, i32x16 (&acc)[NL][2]) {
    const int tid = threadIdx.x, l = tid & 63, w = tid >> 6;
    const int wm = (w & 1) << 6, wn = (w >> 1) << 5;
    const int col = l & 31, kg = l >> 5;
    const int rA = tid >> 2, sl = tid & 3;
    const int cs = (sl ^ ((rA >> 1) & 3)) << 4;
    const u8* Ap = A + (long)(m0 + rA) * 384 + cs;
    const i8* Bp = B + (long)(n0 + rA) * 384 + cs;
    char* dst = lds8 + tid * 16;
    for (int kk = 0; kk < 384; kk += 64) {
        gload16(Ap + kk, dst);                       // A rows 0..63
        gload16(Ap + 24576 + kk, dst + 4096);        // A rows 64..127 (64*384)
        #pragma unroll
        for (int p = 0; p < NL; p++)
            gload16(Bp + p * lstride + kk, dst + 8192 + p * 4096);
        __syncthreads();   // drains vmcnt(0): staged data visible
        #pragma unroll
        for (int c = 0; c < 2; c++) {
            i32x4 af[2];
            #pragma unroll
            for (int i = 0; i < 2; i++) {
                int ra = wm + (i << 5) + col;
                int sa = ((2 * c + kg) ^ ((ra >> 1) & 3)) << 4;
                af[i] = *(const i32x4*)(lds8 + ra * 64 + sa);
            }
            int rb = wn + col;
            int sb = ((2 * c + kg) ^ ((rb >> 1) & 3)) << 4;
            #pragma unroll
            for (int p = 0; p < NL; p++) {
                i32x4 bf = *(const i32x4*)(lds8 + 8192 + p * 4096 + rb * 64 + sb);
                #pragma unroll
                for (int i = 0; i < 2; i++)
                    acc[p][i] = __builtin_amdgcn_mfma_i32_32x32x32_i8(af[i], bf, acc[p][i], 0, 0, 0);
            }
        }
        __syncthreads();
    }
}

// ---------- K2: q/k/v conv1x1 (3-level i8 GEMM) + scale + BN + LIF -> u8 spikes ----------
// grid 4608: per m-tile, 18 subs (6 d-tiles x 3 branches) grouped on one XCD -> A-tile L2-resident.
__global__ __launch_bounds__(256, 4) void k2(
    const u8* __restrict__ Xt, const i8* __restrict__ Wq, const float* __restrict__ Sc,
    const float* __restrict__ g0, const float* __restrict__ b0, const float* __restrict__ m0_, const float* __restrict__ v0_,
    const float* __restrict__ g1, const float* __restrict__ b1, const float* __restrict__ m1_, const float* __restrict__ v1_,
    const float* __restrict__ g2, const float* __restrict__ b2, const float* __restrict__ m2_, const float* __restrict__ v2_,
    u8* __restrict__ oq, u8* __restrict__ ok, u8* __restrict__ ov, float* __restrict__ out1)
{
    __shared__ __attribute__((aligned(16))) char lds8[20480];   // staging 20KB; epilogue tile 128x80 u8 (10240B)
    const int bid = blockIdx.x;
    const int xcd = bid & 7, bi = bid >> 3;
    const int mt = (bi / 18) * 8 + xcd;
    const int sub = bi % 18;
    const int m0 = mt * 128, d0 = (sub % 6) * 64, br = sub / 6;
    const float* G  = br == 0 ? g0  : (br == 1 ? g1  : g2);
    const float* Be = br == 0 ? b0  : (br == 1 ? b1  : b2);
    const float* Mu = br == 0 ? m0_ : (br == 1 ? m1_ : m2_);
    const float* Va = br == 0 ? v0_ : (br == 1 ? v1_ : v2_);

    i32x16 acc[3][2];
    #pragma unroll
    for (int p = 0; p < 3; p++)
        #pragma unroll
        for (int i = 0; i < 2; i++)
            #pragma unroll
            for (int r = 0; r < 16; r++) acc[p][i][r] = 0;
    gemm_i8<3>(Xt, Wq + (long)br * 3 * 147456, 147456L, lds8, m0, d0, acc);

    const int tid = threadIdx.x, l = tid & 63, w = tid >> 6;
    const int wm = (w & 1) << 6, wn = (w >> 1) << 5;
    const int col = l & 31;
    const int d = d0 + wn + col;
    const float scb = G[d] / sqrtf(Va[d] + 1e-5f);
    const float mu = Mu[d], be = Be[d];
    const float wsc = Sc[br * 384 + d];
    u8* tile8 = (u8*)lds8;   // stride 80
    const float c1 = 0.0078125f, c2 = 6.103515625e-05f;
    #pragma unroll
    for (int i = 0; i < 2; i++)
        #pragma unroll
        for (int q = 0; q < 4; q++) {
            float vm = 0.f;
            int mb = wm + (i << 5) + (q << 3) + ((l >> 5) << 2);
            #pragma unroll
            for (int t = 0; t < 4; t++) {
                int reg = q * 4 + t;
                float f = (float)acc[0][i][reg] + (float)acc[1][i][reg] * c1
                        + (float)acc[2][i][reg] * c2;
                float bn = (f * wsc - mu) * scb + be;
                vm += (bn - vm) * 0.5f;
                u8 s = 0;
                if (vm >= 1.0f) { s = 1; vm = 0.f; }
                tile8[(mb + t) * 80 + wn + col] = s;
            }
        }
    __syncthreads();
    // Out8: 128 rows x 64 cols u8, 32B per thread
    const int ml = tid >> 1, cb = (tid & 1) << 5;
    u8* Out8 = br == 0 ? oq : (br == 1 ? ok : ov);
    uint4 w0 = *(const uint4*)&tile8[ml * 80 + cb];
    uint4 w1 = *(const uint4*)&tile8[ml * 80 + cb + 16];
    *(uint4*)&Out8[(long)(m0 + ml) * 384 + d0 + cb] = w0;
    *(uint4*)&Out8[(long)(m0 + ml) * 384 + d0 + cb + 16] = w1;
    if (br == 2) {   // output 1: v spikes as f32 in (T,B,h,N,Ch)
        const int b = m0 >> 10, n_base = (m0 >> 2) & 255;
        const int dl = tid & 63, d2 = d0 + dl;
        const int h = d2 / 48, ch = d2 % 48;
        for (int q = 0; q < 32; q++) {
            int mlq = (tid >> 6) + (q << 2);
            int t = mlq & 3, n = n_base + (mlq >> 2);
            out1[((((long)t * 32 + b) * 8 + h) * 256 + n) * 48 + ch] =
                tile8[mlq * 80 + dl] ? 1.0f : 0.f;
        }
    }
}

// ---------- K3a: kv partial counts (exact int), uchar4 loads ----------
__global__ __launch_bounds__(384) void k3a(const u8* __restrict__ Ks, const u8* __restrict__ Vs,
                                           float* __restrict__ kv_raw) {
    const int b = blockIdx.y, nc = blockIdx.x;
    const int d4 = threadIdx.x * 4, t = threadIdx.y;
    int cnt0 = 0, cnt1 = 0, cnt2 = 0, cnt3 = 0;
    for (int nl = 0; nl < 32; nl++) {
        const long row = ((long)b * 256 + nc * 32 + nl) * 4 + t;
        uchar4 kk = *(const uchar4*)&Ks[row * 384 + d4];
        uchar4 vv = *(const uchar4*)&Vs[row * 384 + d4];
        cnt0 += (kk.x & vv.x); cnt1 += (kk.y & vv.y);
        cnt2 += (kk.z & vv.z); cnt3 += (kk.w & vv.w);
    }
    float* dst = &kv_raw[((long)t * 32 + b) * 384 + d4];
    atomicAdd(dst + 0, (float)cnt0);
    atomicAdd(dst + 1, (float)cnt1);
    atomicAdd(dst + 2, (float)cnt2);
    atomicAdd(dst + 3, (float)cnt3);
}

// ---------- K3b: LIF(kv, v_th=0.5) -> u8 ----------
__global__ __launch_bounds__(384) void k3b(const float* __restrict__ kv_raw, u8* __restrict__ kvs) {
    const int b = blockIdx.x, d = threadIdx.x;
    float vm = 0.f;
    #pragma unroll
    for (int t = 0; t < 4; t++) {
        vm += (kv_raw[((long)t * 32 + b) * 384 + d] - vm) * 0.5f;
        u8 sp = 0;
        if (vm >= 0.5f) { sp = 1; vm = 0.f; }
        kvs[((long)t * 32 + b) * 384 + d] = sp;
    }
}

// ---------- K3c: Y(u8) = q(u8) & KV(u8), 16B per thread ----------
__global__ __launch_bounds__(256) void k3c(const u8* __restrict__ Qs, const u8* __restrict__ KVs,
                                           u8* __restrict__ Y) {
    const long i16 = ((long)blockIdx.x * 256 + threadIdx.x) * 16;
    const int m = (int)(i16 / 384), d16 = (int)(i16 % 384);
    const int t = m & 3, b = m >> 10;
    uint4 q = *(const uint4*)(Qs + i16);
    uint4 kvv = *(const uint4*)(KVs + ((long)(t * 32 + b) * 384 + d16));
    uint4 y;
    y.x = q.x & kvv.x; y.y = q.y & kvv.y; y.z = q.z & kvv.z; y.w = q.w & kvv.w;
    *(uint4*)(Y + i16) = y;
}

// ---------- K4: proj GEMM (2-level i8) + bias + BN + identity -> f32 (T,B,C,H,W) ----------
// grid 1536: per m-tile, 6 e-tiles grouped on one XCD.
__global__ __launch_bounds__(256, 4) void k4(
    const u8* __restrict__ Y, const i8* __restrict__ Pq, const float* __restrict__ Scp,
    const float* __restrict__ PB, const float* __restrict__ PG, const float* __restrict__ PBe,
    const float* __restrict__ PM, const float* __restrict__ PV,
    const float* __restrict__ X, float* __restrict__ O)
{
    __shared__ __attribute__((aligned(16))) char lds8[33792];  // staging 16KB; f32 tile [64][132] = 33792B
    const int bid = blockIdx.x;
    const int xcd = bid & 7, bi = bid >> 3;
    const int mt = (bi / 6) * 8 + xcd;
    const int m0 = mt * 128, e0 = (bi % 6) * 64;
    i32x16 acc[2][2];
    #pragma unroll
    for (int p = 0; p < 2; p++)
        #pragma unroll
        for (int i = 0; i < 2; i++)
            #pragma unroll
            for (int r = 0; r < 16; r++) acc[p][i][r] = 0;
    gemm_i8<2>(Y, Pq, 147456L, lds8, m0, e0, acc);

    const int tid = threadIdx.x, l = tid & 63, w = tid >> 6;
    const int wm = (w & 1) << 6, wn = (w >> 1) << 5;
    const int col = l & 31;
    const int e = e0 + wn + col;
    const float scb = PG[e] / sqrtf(PV[e] + 1e-5f);
    const float mu = PM[e], be = PBe[e], pbb = PB[e];
    const float wsc = Scp[e];
    float* smemf = (float*)lds8;   // [e 64][m 132] transposed: b128 reads + coalesced stores
    const float c1 = 0.0078125f;
    #pragma unroll
    for (int i = 0; i < 2; i++)
        #pragma unroll
        for (int q = 0; q < 4; q++)
            #pragma unroll
            for (int t = 0; t < 4; t++) {
                int reg = q * 4 + t;
                float f = (float)acc[0][i][reg] + (float)acc[1][i][reg] * c1;
                float z = (f * wsc + pbb - mu) * scb + be;
                int m = wm + (i << 5) + (q << 3) + ((l >> 5) << 2) + t;
                smemf[(wn + col) * 132 + m] = z;
            }
    __syncthreads();
    const int b = m0 >> 10, n_base = (m0 >> 2) & 255;
    const int n_l = tid & 31;
    #pragma unroll
    for (int ei = 0; ei < 8; ei++) {
        int e_l = (tid >> 5) + (ei << 3);
        f32x4 v = *(const f32x4*)&smemf[e_l * 132 + (n_l << 2)];
        #pragma unroll
        for (int t = 0; t < 4; t++) {
            long gi = (((long)t * 32 + b) * 384 + e0 + e_l) * 256 + n_base + n_l;
            O[gi] = v[t] + X[gi];
        }
    }
}

extern "C" void kernel_launch(void* const* d_in, const int* in_sizes, int n_in,
                              void* d_out, int out_size, void* d_ws, size_t ws_size,
                              hipStream_t stream) {
    (void)in_sizes; (void)n_in; (void)out_size; (void)ws_size;
    const float* x   = (const float*)d_in[0];
    const float* qw  = (const float*)d_in[1];
    const float* qg  = (const float*)d_in[2];
    const float* qb  = (const float*)d_in[3];
    const float* qm  = (const float*)d_in[4];
    const float* qv  = (const float*)d_in[5];
    const float* kw  = (const float*)d_in[6];
    const float* kg  = (const float*)d_in[7];
    const float* kb  = (const float*)d_in[8];
    const float* km  = (const float*)d_in[9];
    const float* kv  = (const float*)d_in[10];
    const float* vw  = (const float*)d_in[11];
    const float* vg  = (const float*)d_in[12];
    const float* vb  = (const float*)d_in[13];
    const float* vm  = (const float*)d_in[14];
    const float* vv  = (const float*)d_in[15];
    const float* pw  = (const float*)d_in[16];
    const float* pb  = (const float*)d_in[17];
    const float* pg  = (const float*)d_in[18];
    const float* pbe = (const float*)d_in[19];
    const float* pm  = (const float*)d_in[20];
    const float* pv  = (const float*)d_in[21];

    // out0 (50.3 MB) as scratch until k4 writes it:
    //   Qs8 u8 @ [0, 12582912)           (dead after k3c)
    //   Xt8 u8 @ [12582912, 25165824)    (dead after k2)
    // ws: Ks8/Vs8 u8 (-> reused as Y u8 after k3a), KVraw, kvs u8, Wq i8 (11 levels), Sc f32
    float* out0 = (float*)d_out;
    float* out1 = out0 + 12582912;
    char*  ob   = (char*)d_out;
    u8*    Qs8  = (u8*)ob;
    u8*    Xt8  = (u8*)(ob + 12582912);
    char*  ws   = (char*)d_ws;
    u8*    Ks8  = (u8*)ws;
    u8*    Vs8  = (u8*)ws + 12582912;
    u8*    Yb8  = (u8*)ws;                       // reuse Ks8 region after k3a
    float* KVraw = (float*)(ws + 25165824);      // 196608 B
    u8*    KVs8  = (u8*)(ws + 25362432);         // 49152 B
    i8*    Wq    = (i8*)(ws + 25411584);         // 11*147456 = 1622016 B
    float* Sc    = (float*)(ws + 27033600);      // 1536*4 = 6144 B

    hipLaunchKernelGGL(prep, dim3(1152), dim3(256), 0, stream, x, Xt8, qw, kw, vw, pw, Wq, Sc, KVraw);
    hipLaunchKernelGGL(k2, dim3(4608), dim3(256), 0, stream,
                       Xt8, Wq, Sc,
                       qg, qb, qm, qv,
                       kg, kb, km, kv,
                       vg, vb, vm, vv,
                       Qs8, Ks8, Vs8, out1);
    hipLaunchKernelGGL(k3a, dim3(8, 32), dim3(96, 4), 0, stream, Ks8, Vs8, KVraw);
    hipLaunchKernelGGL(k3b, dim3(32), dim3(384), 0, stream, KVraw, KVs8);
    hipLaunchKernelGGL(k3c, dim3(3072), dim3(256), 0, stream, Qs8, KVs8, Yb8);
    hipLaunchKernelGGL(k4, dim3(768 * 2), dim3(256), 0, stream,
                       Yb8, Wq + 9 * 147456L, Sc + 3 * 384, pb, pg, pbe, pm, pv, x, out0);
}

// Round 5
// 286.019 us; speedup vs baseline: 1.2153x; 1.0031x over previous
//
#include <hip/hip_runtime.h>

typedef unsigned short u16;
typedef unsigned char u8;
typedef signed char i8;
typedef int i32x4 __attribute__((ext_vector_type(4)));
typedef int i32x16 __attribute__((ext_vector_type(16)));
typedef float f32x4 __attribute__((ext_vector_type(4)));
typedef unsigned u32x4 __attribute__((ext_vector_type(4)));
typedef u8 u8x16 __attribute__((ext_vector_type(16)));

// Chunked spike layout: buf[ch][m][64], ch = d>>6 (6 chunks), m = (b*256+n)*4+t (32768 rows).
// CHS = 32768*64 bytes. Weights: W[lvl][ck][d][64], lvl stride 147456, ck stride 24576.
#define CHS 2097152L

// async global->LDS, 16B per lane (global_load_lds_dwordx4)
__device__ __forceinline__ void gload16(const void* g, void* l) {
    __builtin_amdgcn_global_load_lds(
        (const __attribute__((address_space(1))) void*)g,
        (__attribute__((address_space(3))) void*)l, 16, 0, 0);
}

// ---------- PREP: fused [k1: shortcut LIF + transpose -> u8 chunked] + [i8 weight levels chunked] ----------
// grid: 768 k1-blocks (3 c-tiles x 8 n-tiles x 32 b) + 384 weight blocks (1 row/wave); block 256
__global__ __launch_bounds__(256) void prep(const float* __restrict__ X, u8* __restrict__ Xt,
    const float* __restrict__ qw, const float* __restrict__ kw,
    const float* __restrict__ vw, const float* __restrict__ pw,
    i8* __restrict__ Wq, float* __restrict__ Sc, float* __restrict__ KVraw) {
    const int bid = blockIdx.x;
    if (bid < 768) {
        // LDS [t][n][c] u8 so the transpose READ is one 16B vector load
        __shared__ __attribute__((aligned(16))) u8 s2[4][32][136];
        const int c0 = (bid % 3) * 128;
        const int n0 = ((bid / 3) & 7) * 32;
        const int b = bid / 24;
        const int n_l = threadIdx.x & 31, cg = threadIdx.x >> 5;
        for (int jj = 0; jj < 16; jj++) {
            int c_l = cg + jj * 8;
            float vm = 0.f;
            #pragma unroll
            for (int t = 0; t < 4; t++) {
                float xv = __builtin_nontemporal_load(&X[(((long)t * 32 + b) * 384 + c0 + c_l) * 256 + n0 + n_l]);
                vm += (xv - vm) * 0.5f;
                u8 sp = 0;
                if (vm >= 1.0f) { sp = 1; vm = 0.f; }
                s2[t][n_l][c_l] = sp;
            }
        }
        __syncthreads();
        const int c16 = (threadIdx.x & 7) << 4;       // 8 lanes x 16B = 128 c
        const int n = (threadIdx.x >> 3) & 31;
        const int cglob = c0 + c16;
        const int ch = cglob >> 6, off = cglob & 63;
        #pragma unroll
        for (int t = 0; t < 4; t++) {
            u8x16 v = *(const u8x16*)&s2[t][n][c16];
            *(u8x16*)&Xt[(long)ch * CHS + ((long)(b * 256 + n0 + n) * 4 + t) * 64 + off] = v;
        }
    } else {
        // i8 3-level (qkv) / 2-level (proj) quantization, one 384-wide row per wave, chunked output
        const int wv = bid - 768;                     // 0..383
        const int w = threadIdx.x >> 6, lane = threadIdx.x & 63;
        const int r = wv * 4 + w;                     // 0..1535
        const int m = r / 384, d = r - m * 384;
        const float* srcs[4] = {qw, kw, vw, pw};
        const float* row = srcs[m] + (long)d * 384;
        float a[6]; float mx = 0.f;
        #pragma unroll
        for (int jj = 0; jj < 6; jj++) { a[jj] = row[lane + (jj << 6)]; mx = fmaxf(mx, fabsf(a[jj])); }
        #pragma unroll
        for (int off = 1; off < 64; off <<= 1) mx = fmaxf(mx, __shfl_xor(mx, off));
        float scale = mx * (1.f / 127.f);
        float sinv = mx > 0.f ? 127.f / mx : 0.f;
        if (lane == 0) Sc[r] = scale;
        i8* dstb = Wq + (long)(m == 3 ? 9 : m * 3) * 147456 + (long)d * 64;
        #pragma unroll
        for (int jj = 0; jj < 6; jj++) {
            float x = a[jj] * sinv;
            float q1 = rintf(x);         float r1 = x - q1;
            float q2 = rintf(r1 * 128.f); float r2 = r1 * 128.f - q2;
            float q3 = rintf(r2 * 128.f);
            int co = jj * 24576 + lane;
            dstb[co] = (i8)(int)q1;
            dstb[147456 + co] = (i8)(int)q2;
            if (m != 3) dstb[2 * 147456 + co] = (i8)(int)q3;
        }
        const int idx = wv * 256 + threadIdx.x;
        if (idx < 49152) KVraw[idx] = 0.f;
    }
}

// ---------- i8 multi-level GEMM: 128x64 tile, BK=64, mfma_i32_32x32x32_i8, gload_lds + XOR swizzle ----------
// A chunked [6][32768][64] (stride CHS); B chunked weights [lvl][6][384][64] (lvl 147456, ck 24576).
// LDS: A [128][64] at 0 (8KB), B level p [64][64] at 8192 + p*4096. Dest byte = tid*16 (wave-linear).
// Swizzle: LDS 16B-slot s of row r holds global slot s ^ ((r>>1)&3); reads apply the same XOR.
// Note cs(rA) == cs(rA+64), so the rows-64..127 A gload shares cs (source offset +4096).
template<int NL>
__device__ __forceinline__ void gemm_i8(const u8* __restrict__ A, const i8* __restrict__ B,
                                        char* lds8, int m0, int n0, i32x16 (&acc)[NL][2]) {
    const int tid = threadIdx.x, l = tid & 63, w = tid >> 6;
    const int wm = (w & 1) << 6, wn = (w >> 1) << 5;
    const int col = l & 31, kg = l >> 5;
    const int rA = tid >> 2, sl = tid & 3;
    const int cs = (sl ^ ((rA >> 1) & 3)) << 4;
    const u8* Ap = A + (long)(m0 + rA) * 64 + cs;
    const i8* Bp = B + (long)(n0 + rA) * 64 + cs;
    char* dst = lds8 + tid * 16;
    for (int ck = 0; ck < 6; ck++) {
        gload16(Ap + ck * CHS, dst);                  // A rows 0..63
        gload16(Ap + ck * CHS + 4096, dst + 4096);    // A rows 64..127
        #pragma unroll
        for (int p = 0; p < NL; p++)
            gload16(Bp + p * 147456 + ck * 24576, dst + 8192 + p * 4096);
        __syncthreads();   // drains vmcnt(0): staged data visible
        #pragma unroll
        for (int c = 0; c < 2; c++) {
            i32x4 af[2];
            #pragma unroll
            for (int i = 0; i < 2; i++) {
                int ra = wm + (i << 5) + col;
                int sa = ((2 * c + kg) ^ ((ra >> 1) & 3)) << 4;
                af[i] = *(const i32x4*)(lds8 + ra * 64 + sa);
            }
            int rb = wn + col;
            int sb = ((2 * c + kg) ^ ((rb >> 1) & 3)) << 4;
            #pragma unroll
            for (int p = 0; p < NL; p++) {
                i32x4 bf = *(const i32x4*)(lds8 + 8192 + p * 4096 + rb * 64 + sb);
                #pragma unroll
                for (int i = 0; i < 2; i++)
                    acc[p][i] = __builtin_amdgcn_mfma_i32_32x32x32_i8(af[i], bf, acc[p][i], 0, 0, 0);
            }
        }
        __syncthreads();
    }
}

// ---------- K2: q/k/v conv1x1 (3-level i8 GEMM) + scale + BN + LIF -> u8 spikes (chunked, NT stores) ----------
// grid 4608: per m-tile, 18 subs (6 d-tiles x 3 branches) grouped on one XCD -> A-tile L2-resident.
__global__ __launch_bounds__(256, 4) void k2(
    const u8* __restrict__ Xt, const i8* __restrict__ Wq, const float* __restrict__ Sc,
    const float* __restrict__ g0, const float* __restrict__ b0, const float* __restrict__ m0_, const float* __restrict__ v0_,
    const float* __restrict__ g1, const float* __restrict__ b1, const float* __restrict__ m1_, const float* __restrict__ v1_,
    const float* __restrict__ g2, const float* __restrict__ b2, const float* __restrict__ m2_, const float* __restrict__ v2_,
    u8* __restrict__ oq, u8* __restrict__ ok, u8* __restrict__ ov, float* __restrict__ out1)
{
    __shared__ __attribute__((aligned(16))) char lds8[20480];   // staging 20KB; epilogue tile 128x80 u8 (10240B)
    const int bid = blockIdx.x;
    const int xcd = bid & 7, bi = bid >> 3;
    const int mt = (bi / 18) * 8 + xcd;
    const int sub = bi % 18;
    const int m0 = mt * 128, d0 = (sub % 6) * 64, br = sub / 6;
    const float* G  = br == 0 ? g0  : (br == 1 ? g1  : g2);
    const float* Be = br == 0 ? b0  : (br == 1 ? b1  : b2);
    const float* Mu = br == 0 ? m0_ : (br == 1 ? m1_ : m2_);
    const float* Va = br == 0 ? v0_ : (br == 1 ? v1_ : v2_);

    i32x16 acc[3][2];
    #pragma unroll
    for (int p = 0; p < 3; p++)
        #pragma unroll
        for (int i = 0; i < 2; i++)
            #pragma unroll
            for (int r = 0; r < 16; r++) acc[p][i][r] = 0;
    gemm_i8<3>(Xt, Wq + (long)br * 3 * 147456, lds8, m0, d0, acc);

    const int tid = threadIdx.x, l = tid & 63, w = tid >> 6;
    const int wm = (w & 1) << 6, wn = (w >> 1) << 5;
    const int col = l & 31;
    const int d = d0 + wn + col;
    const float scb = G[d] / sqrtf(Va[d] + 1e-5f);
    const float mu = Mu[d], be = Be[d];
    const float wsc = Sc[br * 384 + d];
    u8* tile8 = (u8*)lds8;   // stride 80
    const float c1 = 0.0078125f, c2 = 6.103515625e-05f;
    #pragma unroll
    for (int i = 0; i < 2; i++)
        #pragma unroll
        for (int q = 0; q < 4; q++) {
            float vm = 0.f;
            int mb = wm + (i << 5) + (q << 3) + ((l >> 5) << 2);
            #pragma unroll
            for (int t = 0; t < 4; t++) {
                int reg = q * 4 + t;
                float f = (float)acc[0][i][reg] + (float)acc[1][i][reg] * c1
                        + (float)acc[2][i][reg] * c2;
                float bn = (f * wsc - mu) * scb + be;
                vm += (bn - vm) * 0.5f;
                u8 s = 0;
                if (vm >= 1.0f) { s = 1; vm = 0.f; }
                tile8[(mb + t) * 80 + wn + col] = s;
            }
        }
    __syncthreads();
    // Out8 chunked: block writes dense 8KB region [m0..m0+128) x 64 of chunk d0>>6 (NT: consumed cross-XCD)
    const int ml = tid >> 1, cb = (tid & 1) << 5;
    u8* Out8 = br == 0 ? oq : (br == 1 ? ok : ov);
    long obase = (long)(d0 >> 6) * CHS + (long)(m0 + ml) * 64 + cb;
    u32x4 w0 = *(const u32x4*)&tile8[ml * 80 + cb];
    u32x4 w1 = *(const u32x4*)&tile8[ml * 80 + cb + 16];
    __builtin_nontemporal_store(w0, (u32x4*)(Out8 + obase));
    __builtin_nontemporal_store(w1, (u32x4*)(Out8 + obase + 16));
    if (br == 2) {   // output 1: v spikes as f32 in (T,B,h,N,Ch); f32x4 never crosses h (48%4==0)
        const int b = m0 >> 10, n_base = (m0 >> 2) & 255;
        const int dl4 = (tid & 15) << 2;
        const int d2 = d0 + dl4;
        const int h = d2 / 48, chn = d2 - h * 48;
        #pragma unroll
        for (int q = 0; q < 8; q++) {
            int mlq = (tid >> 4) + (q << 4);
            int t = mlq & 3, n = n_base + (mlq >> 2);
            f32x4 v;
            #pragma unroll
            for (int r = 0; r < 4; r++) v[r] = tile8[mlq * 80 + dl4 + r] ? 1.0f : 0.f;
            long gi = ((((long)t * 32 + b) * 8 + h) * 256 + n) * 48 + chn;
            __builtin_nontemporal_store(v, (f32x4*)&out1[gi]);
        }
    }
}

// ---------- K3a: kv partial counts (exact int), uchar4 loads, chunked ----------
__global__ __launch_bounds__(384) void k3a(const u8* __restrict__ Ks, const u8* __restrict__ Vs,
                                           float* __restrict__ kv_raw) {
    const int b = blockIdx.y, nc = blockIdx.x;
    const int d4 = threadIdx.x * 4, t = threadIdx.y;
    const long cbase = (long)(d4 >> 6) * CHS + (d4 & 63);
    int cnt0 = 0, cnt1 = 0, cnt2 = 0, cnt3 = 0;
    for (int nl = 0; nl < 32; nl++) {
        const long row = ((long)b * 256 + nc * 32 + nl) * 4 + t;
        uchar4 kk = *(const uchar4*)&Ks[cbase + row * 64];
        uchar4 vv = *(const uchar4*)&Vs[cbase + row * 64];
        cnt0 += (kk.x & vv.x); cnt1 += (kk.y & vv.y);
        cnt2 += (kk.z & vv.z); cnt3 += (kk.w & vv.w);
    }
    float* dst = &kv_raw[((long)t * 32 + b) * 384 + d4];
    atomicAdd(dst + 0, (float)cnt0);
    atomicAdd(dst + 1, (float)cnt1);
    atomicAdd(dst + 2, (float)cnt2);
    atomicAdd(dst + 3, (float)cnt3);
}

// ---------- K3b: LIF(kv, v_th=0.5) -> u8 ----------
__global__ __launch_bounds__(384) void k3b(const float* __restrict__ kv_raw, u8* __restrict__ kvs) {
    const int b = blockIdx.x, d = threadIdx.x;
    float vm = 0.f;
    #pragma unroll
    for (int t = 0; t < 4; t++) {
        vm += (kv_raw[((long)t * 32 + b) * 384 + d] - vm) * 0.5f;
        u8 sp = 0;
        if (vm >= 0.5f) { sp = 1; vm = 0.f; }
        kvs[((long)t * 32 + b) * 384 + d] = sp;
    }
}

// ---------- K3c: Y(u8) = q(u8) & KV(u8), chunked, 16B per thread ----------
__global__ __launch_bounds__(256) void k3c(const u8* __restrict__ Qs, const u8* __restrict__ KVs,
                                           u8* __restrict__ Y) {
    const int u = blockIdx.x * 256 + threadIdx.x;     // 786432 = 6 ch x 32768 m x 4 off-groups
    const int off16 = (u & 3) << 4;
    const int m = (u >> 2) & 32767;
    const int ch = u >> 17;
    const int t = m & 3, b = m >> 10;
    const long ca = (long)ch * CHS + (long)m * 64 + off16;
    u32x4 q = __builtin_nontemporal_load((const u32x4*)(Qs + ca));
    u32x4 kvv = *(const u32x4*)(KVs + ((long)(t * 32 + b) * 384 + ch * 64 + off16));
    u32x4 y = q & kvv;   // bytes are 0/1: word-AND == byte-AND
    __builtin_nontemporal_store(y, (u32x4*)(Y + ca));
}

// ---------- K4: proj GEMM (2-level i8) + bias + BN + identity -> f32 (T,B,C,H,W) ----------
// grid 1536: per m-tile, 6 e-tiles grouped on one XCD.
__global__ __launch_bounds__(256, 4) void k4(
    const u8* __restrict__ Y, const i8* __restrict__ Pq, const float* __restrict__ Scp,
    const float* __restrict__ PB, const float* __restrict__ PG, const float* __restrict__ PBe,
    const float* __restrict__ PM, const float* __restrict__ PV,
    const float* __restrict__ X, float* __restrict__ O)
{
    __shared__ __attribute__((aligned(16))) char lds8[33792];  // staging 16KB; f32 tile [64][132] = 33792B
    const int bid = blockIdx.x;
    const int xcd = bid & 7, bi = bid >> 3;
    const int mt = (bi / 6) * 8 + xcd;
    const int m0 = mt * 128, e0 = (bi % 6) * 64;
    i32x16 acc[2][2];
    #pragma unroll
    for (int p = 0; p < 2; p++)
        #pragma unroll
        for (int i = 0; i < 2; i++)
            #pragma unroll
            for (int r = 0; r < 16; r++) acc[p][i][r] = 0;
    gemm_i8<2>(Y, Pq, lds8, m0, e0, acc);

    const int tid = threadIdx.x, l = tid & 63, w = tid >> 6;
    const int wm = (w & 1) << 6, wn = (w >> 1) << 5;
    const int col = l & 31;
    const int e = e0 + wn + col;
    const float scb = PG[e] / sqrtf(PV[e] + 1e-5f);
    const float mu = PM[e], be = PBe[e], pbb = PB[e];
    const float wsc = Scp[e];
    float* smemf = (float*)lds8;   // [e 64][m 132] transposed: b128 reads + coalesced stores
    const float c1 = 0.0078125f;
    #pragma unroll
    for (int i = 0; i < 2; i++)
        #pragma unroll
        for (int q = 0; q < 4; q++)
            #pragma unroll
            for (int t = 0; t < 4; t++) {
                int reg = q * 4 + t;
                float f = (float)acc[0][i][reg] + (float)acc[1][i][reg] * c1;
                float z = (f * wsc + pbb - mu) * scb + be;
                int m = wm + (i << 5) + (q << 3) + ((l >> 5) << 2) + t;
                smemf[(wn + col) * 132 + m] = z;
            }
    __syncthreads();
    const int b = m0 >> 10, n_base = (m0 >> 2) & 255;
    const int n_l = tid & 31;
    #pragma unroll
    for (int ei = 0; ei < 8; ei++) {
        int e_l = (tid >> 5) + (ei << 3);
        f32x4 v = *(const f32x4*)&smemf[e_l * 132 + (n_l << 2)];
        #pragma unroll
        for (int t = 0; t < 4; t++) {
            long gi = (((long)t * 32 + b) * 384 + e0 + e_l) * 256 + n_base + n_l;
            float xv = __builtin_nontemporal_load(&X[gi]);
            __builtin_nontemporal_store(v[t] + xv, &O[gi]);
        }
    }
}

extern "C" void kernel_launch(void* const* d_in, const int* in_sizes, int n_in,
                              void* d_out, int out_size, void* d_ws, size_t ws_size,
                              hipStream_t stream) {
    (void)in_sizes; (void)n_in; (void)out_size; (void)ws_size;
    const float* x   = (const float*)d_in[0];
    const float* qw  = (const float*)d_in[1];
    const float* qg  = (const float*)d_in[2];
    const float* qb  = (const float*)d_in[3];
    const float* qm  = (const float*)d_in[4];
    const float* qv  = (const float*)d_in[5];
    const float* kw  = (const float*)d_in[6];
    const float* kg  = (const float*)d_in[7];
    const float* kb  = (const float*)d_in[8];
    const float* km  = (const float*)d_in[9];
    const float* kv  = (const float*)d_in[10];
    const float* vw  = (const float*)d_in[11];
    const float* vg  = (const float*)d_in[12];
    const float* vb  = (const float*)d_in[13];
    const float* vm  = (const float*)d_in[14];
    const float* vv  = (const float*)d_in[15];
    const float* pw  = (const float*)d_in[16];
    const float* pb  = (const float*)d_in[17];
    const float* pg  = (const float*)d_in[18];
    const float* pbe = (const float*)d_in[19];
    const float* pm  = (const float*)d_in[20];
    const float* pv  = (const float*)d_in[21];

    // out0 (50.3 MB) as scratch until k4 writes it:
    //   Qs8 u8 @ [0, 12582912)           (dead after k3c)
    //   Xt8 u8 @ [12582912, 25165824)    (dead after k2)
    // ws: Ks8/Vs8 u8 (-> reused as Y u8 after k3a), KVraw, kvs u8, Wq i8 (11 levels), Sc f32
    float* out0 = (float*)d_out;
    float* out1 = out0 + 12582912;
    char*  ob   = (char*)d_out;
    u8*    Qs8  = (u8*)ob;
    u8*    Xt8  = (u8*)(ob + 12582912);
    char*  ws   = (char*)d_ws;
    u8*    Ks8  = (u8*)ws;
    u8*    Vs8  = (u8*)ws + 12582912;
    u8*    Yb8  = (u8*)ws;                       // reuse Ks8 region after k3a
    float* KVraw = (float*)(ws + 25165824);      // 196608 B
    u8*    KVs8  = (u8*)(ws + 25362432);         // 49152 B
    i8*    Wq    = (i8*)(ws + 25411584);         // 11*147456 = 1622016 B
    float* Sc    = (float*)(ws + 27033600);      // 1536*4 = 6144 B

    hipLaunchKernelGGL(prep, dim3(1152), dim3(256), 0, stream, x, Xt8, qw, kw, vw, pw, Wq, Sc, KVraw);
    hipLaunchKernelGGL(k2, dim3(4608), dim3(256), 0, stream,
                       Xt8, Wq, Sc,
                       qg, qb, qm, qv,
                       kg, kb, km, kv,
                       vg, vb, vm, vv,
                       Qs8, Ks8, Vs8, out1);
    hipLaunchKernelGGL(k3a, dim3(8, 32), dim3(96, 4), 0, stream, Ks8, Vs8, KVraw);
    hipLaunchKernelGGL(k3b, dim3(32), dim3(384), 0, stream, KVraw, KVs8);
    hipLaunchKernelGGL(k3c, dim3(3072), dim3(256), 0, stream, Qs8, KVs8, Yb8);
    hipLaunchKernelGGL(k4, dim3(768 * 2), dim3(256), 0, stream,
                       Yb8, Wq + 9 * 147456L, Sc + 3 * 384, pb, pg, pbe, pm, pv, x, out0);
}

// Round 6
// 263.280 us; speedup vs baseline: 1.3202x; 1.0864x over previous
//
#include <hip/hip_runtime.h>

typedef unsigned short u16;
typedef unsigned char u8;
typedef signed char i8;
typedef int i32x4 __attribute__((ext_vector_type(4)));
typedef int i32x16 __attribute__((ext_vector_type(16)));
typedef float f32x4 __attribute__((ext_vector_type(4)));
typedef unsigned u32x4 __attribute__((ext_vector_type(4)));
typedef u8 u8x16 __attribute__((ext_vector_type(16)));

// Chunked spike layout: buf[ch][m][64], ch = d>>6 (6 chunks), m = (b*256+n)*4+t (32768 rows).
// CHS = 32768*64 bytes. Weights: W[lvl][ck][d][64], lvl stride 147456, ck stride 24576.
#define CHS 2097152L

// async global->LDS, 16B per lane (global_load_lds_dwordx4)
__device__ __forceinline__ void gload16(const void* g, void* l) {
    __builtin_amdgcn_global_load_lds(
        (const __attribute__((address_space(1))) void*)g,
        (__attribute__((address_space(3))) void*)l, 16, 0, 0);
}

// ---------- PREP: fused [k1: shortcut LIF + transpose -> u8 chunked] + [i8 weight levels chunked] ----------
// grid: 768 k1-blocks (3 c-tiles x 8 n-tiles x 32 b) + 384 weight blocks (1 row/wave); block 256
__global__ __launch_bounds__(256) void prep(const float* __restrict__ X, u8* __restrict__ Xt,
    const float* __restrict__ qw, const float* __restrict__ kw,
    const float* __restrict__ vw, const float* __restrict__ pw,
    i8* __restrict__ Wq, float* __restrict__ Sc, float* __restrict__ KVraw) {
    const int bid = blockIdx.x;
    if (bid < 768) {
        // LDS [t][n][c] u8 so the transpose READ is one 16B vector load
        __shared__ __attribute__((aligned(16))) u8 s2[4][32][136];
        const int c0 = (bid % 3) * 128;
        const int n0 = ((bid / 3) & 7) * 32;
        const int b = bid / 24;
        const int n_l = threadIdx.x & 31, cg = threadIdx.x >> 5;
        for (int jj = 0; jj < 16; jj++) {
            int c_l = cg + jj * 8;
            float vm = 0.f;
            #pragma unroll
            for (int t = 0; t < 4; t++) {
                float xv = __builtin_nontemporal_load(&X[(((long)t * 32 + b) * 384 + c0 + c_l) * 256 + n0 + n_l]);
                vm += (xv - vm) * 0.5f;
                u8 sp = 0;
                if (vm >= 1.0f) { sp = 1; vm = 0.f; }
                s2[t][n_l][c_l] = sp;
            }
        }
        __syncthreads();
        const int c16 = (threadIdx.x & 7) << 4;       // 8 lanes x 16B = 128 c
        const int n = (threadIdx.x >> 3) & 31;
        const int cglob = c0 + c16;
        const int ch = cglob >> 6, off = cglob & 63;
        #pragma unroll
        for (int t = 0; t < 4; t++) {
            u8x16 v = *(const u8x16*)&s2[t][n][c16];
            *(u8x16*)&Xt[(long)ch * CHS + ((long)(b * 256 + n0 + n) * 4 + t) * 64 + off] = v;
        }
    } else {
        // i8 3-level (qkv) / 2-level (proj) quantization, one 384-wide row per wave, chunked output
        const int wv = bid - 768;                     // 0..383
        const int w = threadIdx.x >> 6, lane = threadIdx.x & 63;
        const int r = wv * 4 + w;                     // 0..1535
        const int m = r / 384, d = r - m * 384;
        const float* srcs[4] = {qw, kw, vw, pw};
        const float* row = srcs[m] + (long)d * 384;
        float a[6]; float mx = 0.f;
        #pragma unroll
        for (int jj = 0; jj < 6; jj++) { a[jj] = row[lane + (jj << 6)]; mx = fmaxf(mx, fabsf(a[jj])); }
        #pragma unroll
        for (int off = 1; off < 64; off <<= 1) mx = fmaxf(mx, __shfl_xor(mx, off));
        float scale = mx * (1.f / 127.f);
        float sinv = mx > 0.f ? 127.f / mx : 0.f;
        if (lane == 0) Sc[r] = scale;
        i8* dstb = Wq + (long)(m == 3 ? 9 : m * 3) * 147456 + (long)d * 64;
        #pragma unroll
        for (int jj = 0; jj < 6; jj++) {
            float x = a[jj] * sinv;
            float q1 = rintf(x);         float r1 = x - q1;
            float q2 = rintf(r1 * 128.f); float r2 = r1 * 128.f - q2;
            float q3 = rintf(r2 * 128.f);
            int co = jj * 24576 + lane;
            dstb[co] = (i8)(int)q1;
            dstb[147456 + co] = (i8)(int)q2;
            if (m != 3) dstb[2 * 147456 + co] = (i8)(int)q3;
        }
        const int idx = wv * 256 + threadIdx.x;
        if (idx < 49152) KVraw[idx] = 0.f;
    }
}

// ---------- i8 multi-level GEMM: 128x64 tile, BK=64, mfma_i32_32x32x32_i8 ----------
// Ping-pong double-buffered staging (T3-minimum recipe): issue STAGE(ck+1) into buf^1 BEFORE
// compute(ck); ONE __syncthreads per tile (its implicit vmcnt(0) drain lands AFTER the compute
// phase has covered the load latency). Plain barriers only - no raw-barrier races.
// Per-buffer: A [128][64] at +0 (8KB), B level p [64][64] at +8192 + p*4096. BUFSZ=(2+NL)*4KB.
// Dest byte = tid*16 (wave-linear, required). Swizzle: LDS 16B-slot s of row r holds global
// slot s ^ ((r>>1)&3); fragment reads apply the same XOR. cs(rA)==cs(rA+64).
template<int NL>
__device__ __forceinline__ void gemm_i8(const u8* __restrict__ A, const i8* __restrict__ B,
                                        char* lds8, int m0, int n0, i32x16 (&acc)[NL][2]) {
    const int tid = threadIdx.x, l = tid & 63, w = tid >> 6;
    const int wm = (w & 1) << 6, wn = (w >> 1) << 5;
    const int col = l & 31, kg = l >> 5;
    const int rA = tid >> 2, sl = tid & 3;
    const int cs = (sl ^ ((rA >> 1) & 3)) << 4;
    const u8* Ap = A + (long)(m0 + rA) * 64 + cs;
    const i8* Bp = B + (long)(n0 + rA) * 64 + cs;
    const int BUFSZ = (2 + NL) * 4096;
    char* dst = lds8 + tid * 16;

    // prologue: stage tile 0 into buffer 0
    {
        gload16(Ap, dst);
        gload16(Ap + 4096, dst + 4096);
        #pragma unroll
        for (int p = 0; p < NL; p++)
            gload16(Bp + p * 147456, dst + 8192 + p * 4096);
    }
    __syncthreads();
    for (int ck = 0; ck < 6; ck++) {
        const int cur = ck & 1;
        if (ck < 5) {   // prefetch next tile into the other buffer
            char* d = dst + (cur ^ 1) * BUFSZ;
            gload16(Ap + (ck + 1) * CHS, d);
            gload16(Ap + (ck + 1) * CHS + 4096, d + 4096);
            #pragma unroll
            for (int p = 0; p < NL; p++)
                gload16(Bp + p * 147456 + (ck + 1) * 24576, d + 8192 + p * 4096);
        }
        char* base = lds8 + cur * BUFSZ;
        #pragma unroll
        for (int c = 0; c < 2; c++) {
            i32x4 af[2];
            #pragma unroll
            for (int i = 0; i < 2; i++) {
                int ra = wm + (i << 5) + col;
                int sa = ((2 * c + kg) ^ ((ra >> 1) & 3)) << 4;
                af[i] = *(const i32x4*)(base + ra * 64 + sa);
            }
            int rb = wn + col;
            int sb = ((2 * c + kg) ^ ((rb >> 1) & 3)) << 4;
            #pragma unroll
            for (int p = 0; p < NL; p++) {
                i32x4 bf = *(const i32x4*)(base + 8192 + p * 4096 + rb * 64 + sb);
                #pragma unroll
                for (int i = 0; i < 2; i++)
                    acc[p][i] = __builtin_amdgcn_mfma_i32_32x32x32_i8(af[i], bf, acc[p][i], 0, 0, 0);
            }
        }
        __syncthreads();   // drains next-tile loads (overlapped with compute) + syncs buffer reuse
    }
}

// ---------- K2: q/k/v conv1x1 (3-level i8 GEMM) + scale + BN + LIF -> u8 spikes (chunked) ----------
// grid 4608: per m-tile, 18 subs (6 d-tiles x 3 branches) grouped on one XCD -> A-tile L2-resident.
__global__ __launch_bounds__(256, 4) void k2(
    const u8* __restrict__ Xt, const i8* __restrict__ Wq, const float* __restrict__ Sc,
    const float* __restrict__ g0, const float* __restrict__ b0, const float* __restrict__ m0_, const float* __restrict__ v0_,
    const float* __restrict__ g1, const float* __restrict__ b1, const float* __restrict__ m1_, const float* __restrict__ v1_,
    const float* __restrict__ g2, const float* __restrict__ b2, const float* __restrict__ m2_, const float* __restrict__ v2_,
    u8* __restrict__ oq, u8* __restrict__ ok, u8* __restrict__ ov, float* __restrict__ out1)
{
    __shared__ __attribute__((aligned(16))) char lds8[40960];   // 2 x 20KB staging; epilogue tile 128x80 u8 aliased
    const int bid = blockIdx.x;
    const int xcd = bid & 7, bi = bid >> 3;
    const int mt = (bi / 18) * 8 + xcd;
    const int sub = bi % 18;
    const int m0 = mt * 128, d0 = (sub % 6) * 64, br = sub / 6;
    const float* G  = br == 0 ? g0  : (br == 1 ? g1  : g2);
    const float* Be = br == 0 ? b0  : (br == 1 ? b1  : b2);
    const float* Mu = br == 0 ? m0_ : (br == 1 ? m1_ : m2_);
    const float* Va = br == 0 ? v0_ : (br == 1 ? v1_ : v2_);

    i32x16 acc[3][2];
    #pragma unroll
    for (int p = 0; p < 3; p++)
        #pragma unroll
        for (int i = 0; i < 2; i++)
            #pragma unroll
            for (int r = 0; r < 16; r++) acc[p][i][r] = 0;
    gemm_i8<3>(Xt, Wq + (long)br * 3 * 147456, lds8, m0, d0, acc);

    const int tid = threadIdx.x, l = tid & 63, w = tid >> 6;
    const int wm = (w & 1) << 6, wn = (w >> 1) << 5;
    const int col = l & 31;
    const int d = d0 + wn + col;
    const float scb = G[d] / sqrtf(Va[d] + 1e-5f);
    const float mu = Mu[d], be = Be[d];
    const float wsc = Sc[br * 384 + d];
    u8* tile8 = (u8*)lds8;   // stride 80
    const float c1 = 0.0078125f, c2 = 6.103515625e-05f;
    #pragma unroll
    for (int i = 0; i < 2; i++)
        #pragma unroll
        for (int q = 0; q < 4; q++) {
            float vm = 0.f;
            int mb = wm + (i << 5) + (q << 3) + ((l >> 5) << 2);
            #pragma unroll
            for (int t = 0; t < 4; t++) {
                int reg = q * 4 + t;
                float f = (float)acc[0][i][reg] + (float)acc[1][i][reg] * c1
                        + (float)acc[2][i][reg] * c2;
                float bn = (f * wsc - mu) * scb + be;
                vm += (bn - vm) * 0.5f;
                u8 s = 0;
                if (vm >= 1.0f) { s = 1; vm = 0.f; }
                tile8[(mb + t) * 80 + wn + col] = s;
            }
        }
    __syncthreads();
    // Out8 chunked: dense 8KB region, per-instruction-contiguous (lane l -> byte l*16). Cached
    // (no NT): k3a/k3c consume these next launch.
    u8* Out8 = br == 0 ? oq : (br == 1 ? ok : ov);
    const long rbase = (long)(d0 >> 6) * CHS + (long)m0 * 64;
    u32x4 w0 = *(const u32x4*)&tile8[(tid >> 2) * 80 + ((tid & 3) << 4)];
    u32x4 w1 = *(const u32x4*)&tile8[(64 + (tid >> 2)) * 80 + ((tid & 3) << 4)];
    *(u32x4*)(Out8 + rbase + tid * 16) = w0;
    *(u32x4*)(Out8 + rbase + 4096 + tid * 16) = w1;
    if (br == 2) {   // output 1: v spikes as f32 in (T,B,h,N,Ch); final output -> NT, full lines
        const int b = m0 >> 10, n_base = (m0 >> 2) & 255;
        const int dl4 = (tid & 15) << 2;
        const int d2 = d0 + dl4;
        const int h = d2 / 48, chn = d2 - h * 48;
        #pragma unroll
        for (int q = 0; q < 8; q++) {
            int mlq = (tid >> 4) + (q << 4);
            int t = mlq & 3, n = n_base + (mlq >> 2);
            f32x4 v;
            #pragma unroll
            for (int r = 0; r < 4; r++) v[r] = tile8[mlq * 80 + dl4 + r] ? 1.0f : 0.f;
            long gi = ((((long)t * 32 + b) * 8 + h) * 256 + n) * 48 + chn;
            __builtin_nontemporal_store(v, (f32x4*)&out1[gi]);
        }
    }
}

// ---------- K3a: kv partial counts (exact int), uchar4 loads, chunked ----------
__global__ __launch_bounds__(384) void k3a(const u8* __restrict__ Ks, const u8* __restrict__ Vs,
                                           float* __restrict__ kv_raw) {
    const int b = blockIdx.y, nc = blockIdx.x;
    const int d4 = threadIdx.x * 4, t = threadIdx.y;
    const long cbase = (long)(d4 >> 6) * CHS + (d4 & 63);
    int cnt0 = 0, cnt1 = 0, cnt2 = 0, cnt3 = 0;
    for (int nl = 0; nl < 32; nl++) {
        const long row = ((long)b * 256 + nc * 32 + nl) * 4 + t;
        uchar4 kk = *(const uchar4*)&Ks[cbase + row * 64];
        uchar4 vv = *(const uchar4*)&Vs[cbase + row * 64];
        cnt0 += (kk.x & vv.x); cnt1 += (kk.y & vv.y);
        cnt2 += (kk.z & vv.z); cnt3 += (kk.w & vv.w);
    }
    float* dst = &kv_raw[((long)t * 32 + b) * 384 + d4];
    atomicAdd(dst + 0, (float)cnt0);
    atomicAdd(dst + 1, (float)cnt1);
    atomicAdd(dst + 2, (float)cnt2);
    atomicAdd(dst + 3, (float)cnt3);
}

// ---------- K3c (k3b fused): LIF(kv_raw) in-block, then Y(u8) = q(u8) & kvs ----------
// grid 3072 x 256: block covers 64 consecutive m (one b, one chunk), 16B per thread.
__global__ __launch_bounds__(256) void k3c(const u8* __restrict__ Qs, const float* __restrict__ kv_raw,
                                           u8* __restrict__ Y) {
    __shared__ __attribute__((aligned(16))) u8 kvs_s[4][64];
    const int tid = threadIdx.x;
    const int u0 = blockIdx.x << 8;
    const int ch = u0 >> 17;               // constant per block (512 blocks per chunk)
    const int mb = (u0 >> 2) & 32767;      // 64-aligned
    const int b = mb >> 10;                // constant per block (1024 m per b)
    if (tid < 64) {
        float vm = 0.f;
        #pragma unroll
        for (int t = 0; t < 4; t++) {
            vm += (kv_raw[((long)t * 32 + b) * 384 + ch * 64 + tid] - vm) * 0.5f;
            u8 sp = 0;
            if (vm >= 0.5f) { sp = 1; vm = 0.f; }
            kvs_s[t][tid] = sp;
        }
    }
    __syncthreads();
    const int m = mb + (tid >> 2), off16 = (tid & 3) << 4;
    const int t = m & 3;
    const long ca = (long)ch * CHS + (long)m * 64 + off16;
    u32x4 q = *(const u32x4*)(Qs + ca);
    u32x4 kvv = *(const u32x4*)&kvs_s[t][off16];
    u32x4 y = q & kvv;   // bytes are 0/1: word-AND == byte-AND
    *(u32x4*)(Y + ca) = y;
}

// ---------- K4: proj GEMM (2-level i8) + bias + BN + identity -> f32 (T,B,C,H,W) ----------
// grid 1536: per m-tile, 6 e-tiles grouped on one XCD.
__global__ __launch_bounds__(256, 4) void k4(
    const u8* __restrict__ Y, const i8* __restrict__ Pq, const float* __restrict__ Scp,
    const float* __restrict__ PB, const float* __restrict__ PG, const float* __restrict__ PBe,
    const float* __restrict__ PM, const float* __restrict__ PV,
    const float* __restrict__ X, float* __restrict__ O)
{
    __shared__ __attribute__((aligned(16))) char lds8[33792];  // 2 x 16KB staging; f32 tile [64][132] aliased
    const int bid = blockIdx.x;
    const int xcd = bid & 7, bi = bid >> 3;
    const int mt = (bi / 6) * 8 + xcd;
    const int m0 = mt * 128, e0 = (bi % 6) * 64;
    i32x16 acc[2][2];
    #pragma unroll
    for (int p = 0; p < 2; p++)
        #pragma unroll
        for (int i = 0; i < 2; i++)
            #pragma unroll
            for (int r = 0; r < 16; r++) acc[p][i][r] = 0;
    gemm_i8<2>(Y, Pq, lds8, m0, e0, acc);

    const int tid = threadIdx.x, l = tid & 63, w = tid >> 6;
    const int wm = (w & 1) << 6, wn = (w >> 1) << 5;
    const int col = l & 31;
    const int e = e0 + wn + col;
    const float scb = PG[e] / sqrtf(PV[e] + 1e-5f);
    const float mu = PM[e], be = PBe[e], pbb = PB[e];
    const float wsc = Scp[e];
    float* smemf = (float*)lds8;   // [e 64][m 132] transposed: b128 reads + coalesced stores
    const float c1 = 0.0078125f;
    #pragma unroll
    for (int i = 0; i < 2; i++)
        #pragma unroll
        for (int q = 0; q < 4; q++)
            #pragma unroll
            for (int t = 0; t < 4; t++) {
                int reg = q * 4 + t;
                float f = (float)acc[0][i][reg] + (float)acc[1][i][reg] * c1;
                float z = (f * wsc + pbb - mu) * scb + be;
                int m = wm + (i << 5) + (q << 3) + ((l >> 5) << 2) + t;
                smemf[(wn + col) * 132 + m] = z;
            }
    __syncthreads();
    const int b = m0 >> 10, n_base = (m0 >> 2) & 255;
    const int n_l = tid & 31;
    #pragma unroll
    for (int ei = 0; ei < 8; ei++) {
        int e_l = (tid >> 5) + (ei << 3);
        f32x4 v = *(const f32x4*)&smemf[e_l * 132 + (n_l << 2)];
        #pragma unroll
        for (int t = 0; t < 4; t++) {
            long gi = (((long)t * 32 + b) * 384 + e0 + e_l) * 256 + n_base + n_l;
            float xv = __builtin_nontemporal_load(&X[gi]);
            __builtin_nontemporal_store(v[t] + xv, &O[gi]);
        }
    }
}

extern "C" void kernel_launch(void* const* d_in, const int* in_sizes, int n_in,
                              void* d_out, int out_size, void* d_ws, size_t ws_size,
                              hipStream_t stream) {
    (void)in_sizes; (void)n_in; (void)out_size; (void)ws_size;
    const float* x   = (const float*)d_in[0];
    const float* qw  = (const float*)d_in[1];
    const float* qg  = (const float*)d_in[2];
    const float* qb  = (const float*)d_in[3];
    const float* qm  = (const float*)d_in[4];
    const float* qv  = (const float*)d_in[5];
    const float* kw  = (const float*)d_in[6];
    const float* kg  = (const float*)d_in[7];
    const float* kb  = (const float*)d_in[8];
    const float* km  = (const float*)d_in[9];
    const float* kv  = (const float*)d_in[10];
    const float* vw  = (const float*)d_in[11];
    const float* vg  = (const float*)d_in[12];
    const float* vb  = (const float*)d_in[13];
    const float* vm  = (const float*)d_in[14];
    const float* vv  = (const float*)d_in[15];
    const float* pw  = (const float*)d_in[16];
    const float* pb  = (const float*)d_in[17];
    const float* pg  = (const float*)d_in[18];
    const float* pbe = (const float*)d_in[19];
    const float* pm  = (const float*)d_in[20];
    const float* pv  = (const float*)d_in[21];

    // out0 (50.3 MB) as scratch until k4 writes it:
    //   Qs8 u8 @ [0, 12582912)           (dead after k3c)
    //   Xt8 u8 @ [12582912, 25165824)    (dead after k2)
    // ws: Ks8/Vs8 u8 (-> reused as Y u8 after k3a), KVraw, Wq i8 (11 levels), Sc f32
    float* out0 = (float*)d_out;
    float* out1 = out0 + 12582912;
    char*  ob   = (char*)d_out;
    u8*    Qs8  = (u8*)ob;
    u8*    Xt8  = (u8*)(ob + 12582912);
    char*  ws   = (char*)d_ws;
    u8*    Ks8  = (u8*)ws;
    u8*    Vs8  = (u8*)ws + 12582912;
    u8*    Yb8  = (u8*)ws;                       // reuse Ks8 region after k3a
    float* KVraw = (float*)(ws + 25165824);      // 196608 B
    i8*    Wq    = (i8*)(ws + 25411584);         // 11*147456 = 1622016 B
    float* Sc    = (float*)(ws + 27033600);      // 1536*4 = 6144 B

    hipLaunchKernelGGL(prep, dim3(1152), dim3(256), 0, stream, x, Xt8, qw, kw, vw, pw, Wq, Sc, KVraw);
    hipLaunchKernelGGL(k2, dim3(4608), dim3(256), 0, stream,
                       Xt8, Wq, Sc,
                       qg, qb, qm, qv,
                       kg, kb, km, kv,
                       vg, vb, vm, vv,
                       Qs8, Ks8, Vs8, out1);
    hipLaunchKernelGGL(k3a, dim3(8, 32), dim3(96, 4), 0, stream, Ks8, Vs8, KVraw);
    hipLaunchKernelGGL(k3c, dim3(3072), dim3(256), 0, stream, Qs8, KVraw, Yb8);
    hipLaunchKernelGGL(k4, dim3(768 * 2), dim3(256), 0, stream,
                       Yb8, Wq + 9 * 147456L, Sc + 3 * 384, pb, pg, pbe, pm, pv, x, out0);
}

// Round 7
// 259.623 us; speedup vs baseline: 1.3388x; 1.0141x over previous
//
#include <hip/hip_runtime.h>

typedef unsigned short u16;
typedef unsigned char u8;
typedef signed char i8;
typedef int i32x4 __attribute__((ext_vector_type(4)));
typedef int i32x16 __attribute__((ext_vector_type(16)));
typedef float f32x4 __attribute__((ext_vector_type(4)));
typedef unsigned u32x4 __attribute__((ext_vector_type(4)));
typedef u8 u8x16 __attribute__((ext_vector_type(16)));

// Chunked spike layout: buf[ch][m][64], ch = d>>6 (6 chunks), m = (b*256+n)*4+t (32768 rows).
// CHS = 32768*64 bytes. Weights: W[lvl][ck][d][64], lvl stride 147456, ck stride 24576.
#define CHS 2097152L

// async global->LDS, 16B per lane (global_load_lds_dwordx4)
__device__ __forceinline__ void gload16(const void* g, void* l) {
    __builtin_amdgcn_global_load_lds(
        (const __attribute__((address_space(1))) void*)g,
        (__attribute__((address_space(3))) void*)l, 16, 0, 0);
}

// ---------- PREP: fused [k1: shortcut LIF + transpose -> u8 chunked] + [i8 weight levels chunked] ----------
// grid: 768 k1-blocks (3 c-tiles x 8 n-tiles x 32 b) + 384 weight blocks (1 row/wave); block 256
__global__ __launch_bounds__(256) void prep(const float* __restrict__ X, u8* __restrict__ Xt,
    const float* __restrict__ qw, const float* __restrict__ kw,
    const float* __restrict__ vw, const float* __restrict__ pw,
    i8* __restrict__ Wq, float* __restrict__ Sc, float* __restrict__ KVraw) {
    const int bid = blockIdx.x;
    if (bid < 768) {
        // LDS [t][n][c] u8 so the transpose READ is one 16B vector load
        __shared__ __attribute__((aligned(16))) u8 s2[4][32][136];
        const int c0 = (bid % 3) * 128;
        const int n0 = ((bid / 3) & 7) * 32;
        const int b = bid / 24;
        // f32x4 loads: lane handles 4 consecutive n (G13 vectorization)
        const int n4 = (threadIdx.x & 7) << 2;       // 0..28
        const int cl0 = threadIdx.x >> 3;            // 0..31
        #pragma unroll
        for (int pass = 0; pass < 4; pass++) {
            const int c_l = cl0 + (pass << 5);
            f32x4 vm = {0.f, 0.f, 0.f, 0.f};
            #pragma unroll
            for (int t = 0; t < 4; t++) {
                f32x4 xv = __builtin_nontemporal_load(
                    (const f32x4*)&X[(((long)t * 32 + b) * 384 + c0 + c_l) * 256 + n0 + n4]);
                #pragma unroll
                for (int e = 0; e < 4; e++) {
                    vm[e] += (xv[e] - vm[e]) * 0.5f;
                    u8 sp = 0;
                    if (vm[e] >= 1.0f) { sp = 1; vm[e] = 0.f; }
                    s2[t][n4 + e][c_l] = sp;
                }
            }
        }
        __syncthreads();
        const int c16 = (threadIdx.x & 7) << 4;       // 8 lanes x 16B = 128 c
        const int n = (threadIdx.x >> 3) & 31;
        const int cglob = c0 + c16;
        const int ch = cglob >> 6, off = cglob & 63;
        #pragma unroll
        for (int t = 0; t < 4; t++) {
            u8x16 v = *(const u8x16*)&s2[t][n][c16];
            *(u8x16*)&Xt[(long)ch * CHS + ((long)(b * 256 + n0 + n) * 4 + t) * 64 + off] = v;
        }
    } else {
        // i8 3-level (qkv) / 2-level (proj) quantization, one 384-wide row per wave, chunked output
        const int wv = bid - 768;                     // 0..383
        const int w = threadIdx.x >> 6, lane = threadIdx.x & 63;
        const int r = wv * 4 + w;                     // 0..1535
        const int m = r / 384, d = r - m * 384;
        const float* srcs[4] = {qw, kw, vw, pw};
        const float* row = srcs[m] + (long)d * 384;
        float a[6]; float mx = 0.f;
        #pragma unroll
        for (int jj = 0; jj < 6; jj++) { a[jj] = row[lane + (jj << 6)]; mx = fmaxf(mx, fabsf(a[jj])); }
        #pragma unroll
        for (int off = 1; off < 64; off <<= 1) mx = fmaxf(mx, __shfl_xor(mx, off));
        float scale = mx * (1.f / 127.f);
        float sinv = mx > 0.f ? 127.f / mx : 0.f;
        if (lane == 0) Sc[r] = scale;
        i8* dstb = Wq + (long)(m == 3 ? 9 : m * 3) * 147456 + (long)d * 64;
        #pragma unroll
        for (int jj = 0; jj < 6; jj++) {
            float x = a[jj] * sinv;
            float q1 = rintf(x);         float r1 = x - q1;
            float q2 = rintf(r1 * 128.f); float r2 = r1 * 128.f - q2;
            float q3 = rintf(r2 * 128.f);
            int co = jj * 24576 + lane;
            dstb[co] = (i8)(int)q1;
            dstb[147456 + co] = (i8)(int)q2;
            if (m != 3) dstb[2 * 147456 + co] = (i8)(int)q3;
        }
        const int idx = wv * 256 + threadIdx.x;
        if (idx < 49152) KVraw[idx] = 0.f;
    }
}

// ---------- i8 multi-level GEMM: 128x64 tile, BK=64, mfma_i32_32x32x32_i8 ----------
// Ping-pong double-buffered staging: issue STAGE(ck+1) into buf^1 BEFORE compute(ck);
// ONE __syncthreads per tile. Per-buffer: A [128][64] at +0 (8KB), B level p at +8192 + p*4096.
// Dest byte = tid*16 (wave-linear). Swizzle: LDS 16B-slot s of row r holds global slot
// s ^ ((r>>1)&3); fragment reads apply the same XOR. cs(rA)==cs(rA+64).
template<int NL>
__device__ __forceinline__ void gemm_i8(const u8* __restrict__ A, const i8* __restrict__ B,
                                        char* lds8, int m0, int n0, i32x16 (&acc)[NL][2]) {
    const int tid = threadIdx.x, l = tid & 63, w = tid >> 6;
    const int wm = (w & 1) << 6, wn = (w >> 1) << 5;
    const int col = l & 31, kg = l >> 5;
    const int rA = tid >> 2, sl = tid & 3;
    const int cs = (sl ^ ((rA >> 1) & 3)) << 4;
    const u8* Ap = A + (long)(m0 + rA) * 64 + cs;
    const i8* Bp = B + (long)(n0 + rA) * 64 + cs;
    const int BUFSZ = (2 + NL) * 4096;
    char* dst = lds8 + tid * 16;

    // prologue: stage tile 0 into buffer 0
    {
        gload16(Ap, dst);
        gload16(Ap + 4096, dst + 4096);
        #pragma unroll
        for (int p = 0; p < NL; p++)
            gload16(Bp + p * 147456, dst + 8192 + p * 4096);
    }
    __syncthreads();
    for (int ck = 0; ck < 6; ck++) {
        const int cur = ck & 1;
        if (ck < 5) {   // prefetch next tile into the other buffer
            char* d = dst + (cur ^ 1) * BUFSZ;
            gload16(Ap + (ck + 1) * CHS, d);
            gload16(Ap + (ck + 1) * CHS + 4096, d + 4096);
            #pragma unroll
            for (int p = 0; p < NL; p++)
                gload16(Bp + p * 147456 + (ck + 1) * 24576, d + 8192 + p * 4096);
        }
        char* base = lds8 + cur * BUFSZ;
        #pragma unroll
        for (int c = 0; c < 2; c++) {
            i32x4 af[2];
            #pragma unroll
            for (int i = 0; i < 2; i++) {
                int ra = wm + (i << 5) + col;
                int sa = ((2 * c + kg) ^ ((ra >> 1) & 3)) << 4;
                af[i] = *(const i32x4*)(base + ra * 64 + sa);
            }
            int rb = wn + col;
            int sb = ((2 * c + kg) ^ ((rb >> 1) & 3)) << 4;
            #pragma unroll
            for (int p = 0; p < NL; p++) {
                i32x4 bf = *(const i32x4*)(base + 8192 + p * 4096 + rb * 64 + sb);
                #pragma unroll
                for (int i = 0; i < 2; i++)
                    acc[p][i] = __builtin_amdgcn_mfma_i32_32x32x32_i8(af[i], bf, acc[p][i], 0, 0, 0);
            }
        }
        __syncthreads();   // drains next-tile loads (overlapped with compute) + syncs buffer reuse
    }
}

// ---------- K2: q/k/v conv1x1 (3-level i8 GEMM) + scale + BN + LIF -> u8 spikes (chunked) ----------
// grid 4608: per m-tile, 18 subs (6 d-tiles x 3 branches) grouped on one XCD -> A-tile L2-resident.
__global__ __launch_bounds__(256, 4) void k2(
    const u8* __restrict__ Xt, const i8* __restrict__ Wq, const float* __restrict__ Sc,
    const float* __restrict__ g0, const float* __restrict__ b0, const float* __restrict__ m0_, const float* __restrict__ v0_,
    const float* __restrict__ g1, const float* __restrict__ b1, const float* __restrict__ m1_, const float* __restrict__ v1_,
    const float* __restrict__ g2, const float* __restrict__ b2, const float* __restrict__ m2_, const float* __restrict__ v2_,
    u8* __restrict__ oq, u8* __restrict__ ok, u8* __restrict__ ov, float* __restrict__ out1)
{
    __shared__ __attribute__((aligned(16))) char lds8[40960];   // 2 x 20KB staging; epilogue tile 128x80 u8 aliased
    const int bid = blockIdx.x;
    const int xcd = bid & 7, bi = bid >> 3;
    const int mt = (bi / 18) * 8 + xcd;
    const int sub = bi % 18;
    const int m0 = mt * 128, d0 = (sub % 6) * 64, br = sub / 6;
    const float* G  = br == 0 ? g0  : (br == 1 ? g1  : g2);
    const float* Be = br == 0 ? b0  : (br == 1 ? b1  : b2);
    const float* Mu = br == 0 ? m0_ : (br == 1 ? m1_ : m2_);
    const float* Va = br == 0 ? v0_ : (br == 1 ? v1_ : v2_);

    i32x16 acc[3][2];
    #pragma unroll
    for (int p = 0; p < 3; p++)
        #pragma unroll
        for (int i = 0; i < 2; i++)
            #pragma unroll
            for (int r = 0; r < 16; r++) acc[p][i][r] = 0;
    gemm_i8<3>(Xt, Wq + (long)br * 3 * 147456, lds8, m0, d0, acc);

    const int tid = threadIdx.x, l = tid & 63, w = tid >> 6;
    const int wm = (w & 1) << 6, wn = (w >> 1) << 5;
    const int col = l & 31;
    const int d = d0 + wn + col;
    const float scb = G[d] / sqrtf(Va[d] + 1e-5f);
    const float mu = Mu[d], be = Be[d];
    const float wsc = Sc[br * 384 + d];
    u8* tile8 = (u8*)lds8;   // stride 80
    const float c1 = 0.0078125f, c2 = 6.103515625e-05f;
    #pragma unroll
    for (int i = 0; i < 2; i++)
        #pragma unroll
        for (int q = 0; q < 4; q++) {
            float vm = 0.f;
            int mb = wm + (i << 5) + (q << 3) + ((l >> 5) << 2);
            #pragma unroll
            for (int t = 0; t < 4; t++) {
                int reg = q * 4 + t;
                float f = (float)acc[0][i][reg] + (float)acc[1][i][reg] * c1
                        + (float)acc[2][i][reg] * c2;
                float bn = (f * wsc - mu) * scb + be;
                vm += (bn - vm) * 0.5f;
                u8 s = 0;
                if (vm >= 1.0f) { s = 1; vm = 0.f; }
                tile8[(mb + t) * 80 + wn + col] = s;
            }
        }
    __syncthreads();
    // Out8 chunked: dense 8KB region, per-instruction-contiguous (lane l -> byte l*16). Cached
    // (no NT): k3a/k4 consume these next launch.
    u8* Out8 = br == 0 ? oq : (br == 1 ? ok : ov);
    const long rbase = (long)(d0 >> 6) * CHS + (long)m0 * 64;
    u32x4 w0 = *(const u32x4*)&tile8[(tid >> 2) * 80 + ((tid & 3) << 4)];
    u32x4 w1 = *(const u32x4*)&tile8[(64 + (tid >> 2)) * 80 + ((tid & 3) << 4)];
    *(u32x4*)(Out8 + rbase + tid * 16) = w0;
    *(u32x4*)(Out8 + rbase + 4096 + tid * 16) = w1;
    if (br == 2) {   // output 1: v spikes as f32 in (T,B,h,N,Ch); final output -> NT, full lines
        const int b = m0 >> 10, n_base = (m0 >> 2) & 255;
        const int dl4 = (tid & 15) << 2;
        const int d2 = d0 + dl4;
        const int h = d2 / 48, chn = d2 - h * 48;
        #pragma unroll
        for (int q = 0; q < 8; q++) {
            int mlq = (tid >> 4) + (q << 4);
            int t = mlq & 3, n = n_base + (mlq >> 2);
            f32x4 v;
            #pragma unroll
            for (int r = 0; r < 4; r++) v[r] = tile8[mlq * 80 + dl4 + r] ? 1.0f : 0.f;
            long gi = ((((long)t * 32 + b) * 8 + h) * 256 + n) * 48 + chn;
            __builtin_nontemporal_store(v, (f32x4*)&out1[gi]);
        }
    }
}

// ---------- K3a: kv partial counts (exact int), uchar4 loads, chunked ----------
__global__ __launch_bounds__(384) void k3a(const u8* __restrict__ Ks, const u8* __restrict__ Vs,
                                           float* __restrict__ kv_raw) {
    const int b = blockIdx.y, nc = blockIdx.x;
    const int d4 = threadIdx.x * 4, t = threadIdx.y;
    const long cbase = (long)(d4 >> 6) * CHS + (d4 & 63);
    int cnt0 = 0, cnt1 = 0, cnt2 = 0, cnt3 = 0;
    for (int nl = 0; nl < 32; nl++) {
        const long row = ((long)b * 256 + nc * 32 + nl) * 4 + t;
        uchar4 kk = *(const uchar4*)&Ks[cbase + row * 64];
        uchar4 vv = *(const uchar4*)&Vs[cbase + row * 64];
        cnt0 += (kk.x & vv.x); cnt1 += (kk.y & vv.y);
        cnt2 += (kk.z & vv.z); cnt3 += (kk.w & vv.w);
    }
    float* dst = &kv_raw[((long)t * 32 + b) * 384 + d4];
    atomicAdd(dst + 0, (float)cnt0);
    atomicAdd(dst + 1, (float)cnt1);
    atomicAdd(dst + 2, (float)cnt2);
    atomicAdd(dst + 3, (float)cnt3);
}

// ---------- K4: [k3b LIF mask + k3c AND fused] proj GEMM (2-level i8) + bias + BN + identity -> f32 ----------
// grid 1536: per m-tile, 6 e-tiles grouped on one XCD. A = (Qs & kvs-mask) reg-staged (T14);
// B levels via gload_lds. Mask computed per-block from kv_raw (b is fixed per block).
__global__ __launch_bounds__(256, 4) void k4(
    const u8* __restrict__ Qs, const float* __restrict__ kv_raw,
    const i8* __restrict__ Pq, const float* __restrict__ Scp,
    const float* __restrict__ PB, const float* __restrict__ PG, const float* __restrict__ PBe,
    const float* __restrict__ PM, const float* __restrict__ PV,
    const float* __restrict__ X, float* __restrict__ O)
{
    // [0,32768): 2 x 16KB staging dbuf; [0,33792): f32 epilogue tile [64][132] (aliases staging);
    // [33792,35328): kvs mask u8[4][384] (persistent).
    __shared__ __attribute__((aligned(16))) char lds8[35328];
    u8* kvs_s = (u8*)(lds8 + 33792);
    const int bid = blockIdx.x;
    const int xcd = bid & 7, bi = bid >> 3;
    const int mt = (bi / 6) * 8 + xcd;
    const int m0 = mt * 128, e0 = (bi % 6) * 64;
    const int tid = threadIdx.x;
    const int b = m0 >> 10;

    // ---- mask prologue: LIF(kv_raw, v_th=0.5) for this b ----
    for (int dd = tid; dd < 384; dd += 256) {
        float vm = 0.f;
        #pragma unroll
        for (int t = 0; t < 4; t++) {
            vm += (kv_raw[((long)t * 32 + b) * 384 + dd] - vm) * 0.5f;
            u8 sp = 0;
            if (vm >= 0.5f) { sp = 1; vm = 0.f; }
            kvs_s[t * 384 + dd] = sp;
        }
    }
    __syncthreads();

    // ---- GEMM: reg-staged A (= Qs & mask), gload_lds B, ping-pong single-barrier ----
    i32x16 acc[2][2];
    #pragma unroll
    for (int p = 0; p < 2; p++)
        #pragma unroll
        for (int i = 0; i < 2; i++)
            #pragma unroll
            for (int r = 0; r < 16; r++) acc[p][i][r] = 0;
    const int l = tid & 63, w = tid >> 6;
    const int wm = (w & 1) << 6, wn = (w >> 1) << 5;
    const int col = l & 31, kg = l >> 5;
    const int rA = tid >> 2, sl = tid & 3;
    const int cs = (sl ^ ((rA >> 1) & 3)) << 4;
    const int tA = rA & 3;                        // t of both staged rows (rA and rA+64)
    const u8* Ap = Qs + (long)(m0 + rA) * 64 + cs;
    const i8* Bp = Pq + (long)(e0 + rA) * 64 + cs;
    const int BUFSZ = 16384;
    char* dst = lds8 + tid * 16;
    {   // stage tile 0 into buffer 0
        u32x4 mk = *(const u32x4*)&kvs_s[tA * 384 + cs];
        u32x4 q0 = *(const u32x4*)(Ap);
        u32x4 q1 = *(const u32x4*)(Ap + 4096);
        gload16(Bp, dst + 8192);
        gload16(Bp + 147456, dst + 12288);
        *(u32x4*)dst = q0 & mk;
        *(u32x4*)(dst + 4096) = q1 & mk;
    }
    __syncthreads();
    for (int ck = 0; ck < 6; ck++) {
        const int cur = ck & 1;
        if (ck < 5) {   // prefetch next tile into the other buffer
            char* dn = dst + (cur ^ 1) * BUFSZ;
            u32x4 mk = *(const u32x4*)&kvs_s[tA * 384 + (ck + 1) * 64 + cs];
            u32x4 q0 = *(const u32x4*)(Ap + (ck + 1) * CHS);
            u32x4 q1 = *(const u32x4*)(Ap + (ck + 1) * CHS + 4096);
            gload16(Bp + (ck + 1) * 24576, dn + 8192);
            gload16(Bp + 147456 + (ck + 1) * 24576, dn + 12288);
            *(u32x4*)dn = q0 & mk;
            *(u32x4*)(dn + 4096) = q1 & mk;
        }
        char* base = lds8 + cur * BUFSZ;
        #pragma unroll
        for (int c = 0; c < 2; c++) {
            i32x4 af[2];
            #pragma unroll
            for (int i = 0; i < 2; i++) {
                int ra = wm + (i << 5) + col;
                int sa = ((2 * c + kg) ^ ((ra >> 1) & 3)) << 4;
                af[i] = *(const i32x4*)(base + ra * 64 + sa);
            }
            int rb = wn + col;
            int sb = ((2 * c + kg) ^ ((rb >> 1) & 3)) << 4;
            #pragma unroll
            for (int p = 0; p < 2; p++) {
                i32x4 bf = *(const i32x4*)(base + 8192 + p * 4096 + rb * 64 + sb);
                #pragma unroll
                for (int i = 0; i < 2; i++)
                    acc[p][i] = __builtin_amdgcn_mfma_i32_32x32x32_i8(af[i], bf, acc[p][i], 0, 0, 0);
            }
        }
        __syncthreads();
    }

    // ---- epilogue: scale + bias + BN, transpose via LDS, identity add, NT out ----
    const int e = e0 + wn + col;
    const float scb = PG[e] / sqrtf(PV[e] + 1e-5f);
    const float mu = PM[e], be = PBe[e], pbb = PB[e];
    const float wsc = Scp[e];
    float* smemf = (float*)lds8;   // [e 64][m 132] transposed: b128 reads + coalesced stores
    const float c1 = 0.0078125f;
    #pragma unroll
    for (int i = 0; i < 2; i++)
        #pragma unroll
        for (int q = 0; q < 4; q++)
            #pragma unroll
            for (int t = 0; t < 4; t++) {
                int reg = q * 4 + t;
                float f = (float)acc[0][i][reg] + (float)acc[1][i][reg] * c1;
                float z = (f * wsc + pbb - mu) * scb + be;
                int m = wm + (i << 5) + (q << 3) + ((l >> 5) << 2) + t;
                smemf[(wn + col) * 132 + m] = z;
            }
    __syncthreads();
    const int n_base = (m0 >> 2) & 255;
    const int n_l = tid & 31;
    #pragma unroll
    for (int ei = 0; ei < 8; ei++) {
        int e_l = (tid >> 5) + (ei << 3);
        f32x4 v = *(const f32x4*)&smemf[e_l * 132 + (n_l << 2)];
        #pragma unroll
        for (int t = 0; t < 4; t++) {
            long gi = (((long)t * 32 + b) * 384 + e0 + e_l) * 256 + n_base + n_l;
            float xv = __builtin_nontemporal_load(&X[gi]);
            __builtin_nontemporal_store(v[t] + xv, &O[gi]);
        }
    }
}

extern "C" void kernel_launch(void* const* d_in, const int* in_sizes, int n_in,
                              void* d_out, int out_size, void* d_ws, size_t ws_size,
                              hipStream_t stream) {
    (void)in_sizes; (void)n_in; (void)out_size; (void)ws_size;
    const float* x   = (const float*)d_in[0];
    const float* qw  = (const float*)d_in[1];
    const float* qg  = (const float*)d_in[2];
    const float* qb  = (const float*)d_in[3];
    const float* qm  = (const float*)d_in[4];
    const float* qv  = (const float*)d_in[5];
    const float* kw  = (const float*)d_in[6];
    const float* kg  = (const float*)d_in[7];
    const float* kb  = (const float*)d_in[8];
    const float* km  = (const float*)d_in[9];
    const float* kv  = (const float*)d_in[10];
    const float* vw  = (const float*)d_in[11];
    const float* vg  = (const float*)d_in[12];
    const float* vb  = (const float*)d_in[13];
    const float* vm  = (const float*)d_in[14];
    const float* vv  = (const float*)d_in[15];
    const float* pw  = (const float*)d_in[16];
    const float* pb  = (const float*)d_in[17];
    const float* pg  = (const float*)d_in[18];
    const float* pbe = (const float*)d_in[19];
    const float* pm  = (const float*)d_in[20];
    const float* pv  = (const float*)d_in[21];

    // out0 (50.3 MB) as scratch until k4 writes it:
    //   Qs8 u8 @ [0, 12582912)           (read by k4 directly; dead after k4)
    //   Xt8 u8 @ [12582912, 25165824)    (dead after k2)
    // ws: Ks8/Vs8 u8, KVraw, Wq i8 (11 levels), Sc f32
    float* out0 = (float*)d_out;
    float* out1 = out0 + 12582912;
    char*  ob   = (char*)d_out;
    u8*    Qs8  = (u8*)ob;
    u8*    Xt8  = (u8*)(ob + 12582912);
    char*  ws   = (char*)d_ws;
    u8*    Ks8  = (u8*)ws;
    u8*    Vs8  = (u8*)ws + 12582912;
    float* KVraw = (float*)(ws + 25165824);      // 196608 B
    i8*    Wq    = (i8*)(ws + 25411584);         // 11*147456 = 1622016 B
    float* Sc    = (float*)(ws + 27033600);      // 1536*4 = 6144 B

    hipLaunchKernelGGL(prep, dim3(1152), dim3(256), 0, stream, x, Xt8, qw, kw, vw, pw, Wq, Sc, KVraw);
    hipLaunchKernelGGL(k2, dim3(4608), dim3(256), 0, stream,
                       Xt8, Wq, Sc,
                       qg, qb, qm, qv,
                       kg, kb, km, kv,
                       vg, vb, vm, vv,
                       Qs8, Ks8, Vs8, out1);
    hipLaunchKernelGGL(k3a, dim3(8, 32), dim3(96, 4), 0, stream, Ks8, Vs8, KVraw);
    hipLaunchKernelGGL(k4, dim3(1536), dim3(256), 0, stream,
                       Qs8, KVraw, Wq + 9 * 147456L, Sc + 3 * 384, pb, pg, pbe, pm, pv, x, out0);
}